// Round 1
// baseline (29777.939 us; speedup 1.0000x reference)
//
#include <hip/hip_runtime.h>
#include <hip/hip_bf16.h>
#include <math.h>

// GPT-2 small forward: L=12, T=1024, D=1024, H=16, HD=64, V=50257, B=1
#define Lnum 12
#define Tn 1024
#define Dm 1024
#define Hn 16
#define HDn 64
#define Vn 50257

__device__ __forceinline__ float gelu_f(float x) {
    const float c = 0.7978845608028654f; // sqrt(2/pi)
    return 0.5f * x * (1.0f + tanhf(c * (x + 0.044715f * x * x * x)));
}

// ---------------- embedding ----------------
__global__ __launch_bounds__(256) void embed_k(const int* __restrict__ x,
                                               const float* __restrict__ tok,
                                               const float* __restrict__ pos,
                                               float* __restrict__ h) {
    int t = blockIdx.x;
    int id = x[t];
    const float* tr = tok + (size_t)id * Dm;
    const float* pr = pos + (size_t)t * Dm;
    float* hr = h + (size_t)t * Dm;
    for (int i = threadIdx.x; i < Dm; i += 256) hr[i] = tr[i] + pr[i];
}

// ---------------- layernorm ----------------
__global__ __launch_bounds__(256) void ln_k(const float* __restrict__ x,
                                            const float* __restrict__ g,
                                            const float* __restrict__ b,
                                            float* __restrict__ y) {
    int row = blockIdx.x;
    int tid = threadIdx.x;
    const float* xr = x + (size_t)row * Dm;
    float s = 0.f, s2 = 0.f;
    for (int i = tid; i < Dm; i += 256) { float v = xr[i]; s += v; s2 += v * v; }
    __shared__ float rs[256], rs2[256];
    rs[tid] = s; rs2[tid] = s2;
    __syncthreads();
    for (int off = 128; off; off >>= 1) {
        if (tid < off) { rs[tid] += rs[tid + off]; rs2[tid] += rs2[tid + off]; }
        __syncthreads();
    }
    float mean = rs[0] * (1.0f / Dm);
    float var = rs2[0] * (1.0f / Dm) - mean * mean;
    float inv = rsqrtf(var + 1e-5f);
    float* yr = y + (size_t)row * Dm;
    for (int i = tid; i < Dm; i += 256) yr[i] = (xr[i] - mean) * inv * g[i] + b[i];
}

// ---------------- GEMM: C[M,N] = act(A[M,K] @ B + bias) + resid ----------------
// BT=false: B is K x N row-major.  BT=true: B is N x K row-major (B transposed).
// ACT: 0 = none, 1 = gelu.
#define BM 64
#define BN 64
#define BKG 16

template <bool BT, int ACT>
__global__ __launch_bounds__(256) void gemm_k(const float* __restrict__ A,
                                              const float* __restrict__ B,
                                              const float* __restrict__ bias,
                                              const float* __restrict__ resid,
                                              float* __restrict__ C,
                                              int M, int N, int K) {
    __shared__ float As[BKG][BM + 1];
    __shared__ float Bs[BKG][BN + 1];
    int bm = blockIdx.y * BM;
    int bn = blockIdx.x * BN;
    int tid = threadIdx.x;
    int tr = tid >> 4;   // 0..15
    int tc = tid & 15;   // 0..15
    float acc[4][4] = {};

    for (int k0 = 0; k0 < K; k0 += BKG) {
        for (int i = tid; i < BM * BKG; i += 256) {
            int r = i / BKG, c = i % BKG;
            As[c][r] = A[(size_t)(bm + r) * K + k0 + c];
        }
        if (!BT) {
            for (int i = tid; i < BKG * BN; i += 256) {
                int r = i / BN, c = i % BN;
                int col = bn + c;
                Bs[r][c] = (col < N) ? B[(size_t)(k0 + r) * N + col] : 0.f;
            }
        } else {
            for (int i = tid; i < BKG * BN; i += 256) {
                int c = i / BKG, r = i % BKG;
                int col = bn + c;
                Bs[r][c] = (col < N) ? B[(size_t)col * K + k0 + r] : 0.f;
            }
        }
        __syncthreads();
#pragma unroll
        for (int kk = 0; kk < BKG; ++kk) {
            float a[4], bb[4];
#pragma unroll
            for (int i = 0; i < 4; ++i) a[i] = As[kk][tr * 4 + i];
#pragma unroll
            for (int j = 0; j < 4; ++j) bb[j] = Bs[kk][tc * 4 + j];
#pragma unroll
            for (int i = 0; i < 4; ++i)
#pragma unroll
                for (int j = 0; j < 4; ++j) acc[i][j] += a[i] * bb[j];
        }
        __syncthreads();
    }

#pragma unroll
    for (int i = 0; i < 4; ++i) {
        int r = bm + tr * 4 + i;
#pragma unroll
        for (int j = 0; j < 4; ++j) {
            int c = bn + tc * 4 + j;
            if (c < N) {
                float v = acc[i][j];
                if (bias) v += bias[c];
                if (ACT == 1) v = gelu_f(v);
                size_t idx = (size_t)r * N + c;
                if (resid) v += resid[idx];
                C[idx] = v;
            }
        }
    }
}

// ---------------- attention (one block per (query t, head h)) ----------------
__global__ __launch_bounds__(256) void attn_k(const float* __restrict__ qkv,
                                              const float* __restrict__ amask,
                                              float* __restrict__ out) {
    int t = blockIdx.x;
    int hh = blockIdx.y;
    int tid = threadIdx.x;
    __shared__ float q[HDn];
    __shared__ float s[Tn];
    __shared__ float red[256];
    __shared__ float part[4][HDn];

    const float* qrow = qkv + (size_t)t * (3 * Dm) + hh * HDn;
    if (tid < HDn) q[tid] = qrow[tid];
    __syncthreads();

    int nk = t + 1;
    for (int k = tid; k < nk; k += 256) {
        const float* krow = qkv + (size_t)k * (3 * Dm) + Dm + hh * HDn;
        float d = 0.f;
#pragma unroll
        for (int i = 0; i < HDn; ++i) d += q[i] * krow[i];
        d *= 0.125f;                       // 1/sqrt(64)
        d += (1.0f - amask[k]) * -1e30f;   // attention_mask (all ones here)
        s[k] = d;
    }
    __syncthreads();

    // max reduce
    float m = -INFINITY;
    for (int k = tid; k < nk; k += 256) m = fmaxf(m, s[k]);
    red[tid] = m;
    __syncthreads();
    for (int off = 128; off; off >>= 1) {
        if (tid < off) red[tid] = fmaxf(red[tid], red[tid + off]);
        __syncthreads();
    }
    m = red[0];
    __syncthreads();

    // exp + sum reduce
    float sum = 0.f;
    for (int k = tid; k < nk; k += 256) { float e = expf(s[k] - m); s[k] = e; sum += e; }
    red[tid] = sum;
    __syncthreads();
    for (int off = 128; off; off >>= 1) {
        if (tid < off) red[tid] += red[tid + off];
        __syncthreads();
    }
    float inv = 1.0f / red[0];
    __syncthreads();

    // weighted sum of V
    int d = tid & 63;
    int g = tid >> 6;  // 0..3
    float acc = 0.f;
    for (int k = g; k < nk; k += 4)
        acc += s[k] * qkv[(size_t)k * (3 * Dm) + 2 * Dm + hh * HDn + d];
    part[g][d] = acc;
    __syncthreads();
    if (tid < HDn) {
        float v = (part[0][tid] + part[1][tid] + part[2][tid] + part[3][tid]) * inv;
        out[(size_t)t * Dm + hh * HDn + tid] = v;
    }
}

// ---------------- launch ----------------
extern "C" void kernel_launch(void* const* d_in, const int* in_sizes, int n_in,
                              void* d_out, int out_size, void* d_ws, size_t ws_size,
                              hipStream_t stream) {
    const int*   x      = (const int*)d_in[0];
    const float* amask  = (const float*)d_in[1];
    const float* tok    = (const float*)d_in[2];
    const float* pos    = (const float*)d_in[3];
    const float* ln1_g  = (const float*)d_in[4];
    const float* ln1_b  = (const float*)d_in[5];
    const float* qkv_w  = (const float*)d_in[6];
    const float* qkv_b  = (const float*)d_in[7];
    const float* out_w  = (const float*)d_in[8];
    const float* out_b  = (const float*)d_in[9];
    const float* ln2_g  = (const float*)d_in[10];
    const float* ln2_b  = (const float*)d_in[11];
    const float* fc1_w  = (const float*)d_in[12];
    const float* fc1_b  = (const float*)d_in[13];
    const float* fc2_w  = (const float*)d_in[14];
    const float* fc2_b  = (const float*)d_in[15];
    const float* lnf_g  = (const float*)d_in[16];
    const float* lnf_b  = (const float*)d_in[17];
    const float* lm_w   = (const float*)d_in[18];

    float* ws = (float*)d_ws;
    float* h   = ws;                                   // T*D
    float* xn  = ws + (size_t)Tn * Dm;                 // T*D
    float* wv  = ws + 2 * (size_t)Tn * Dm;             // T*D
    // big intermediates live in d_out (fully overwritten by final LM-head GEMM)
    float* outf = (float*)d_out;
    float* qkv  = outf;                                // T*3D = 3.1M floats
    float* ff1  = outf + (size_t)4 * Tn * Dm;          // T*4D = 4.2M floats

    embed_k<<<Tn, 256, 0, stream>>>(x, tok, pos, h);

    for (int l = 0; l < Lnum; ++l) {
        const float* l1g = ln1_g + (size_t)l * Dm;
        const float* l1b = ln1_b + (size_t)l * Dm;
        const float* qw  = qkv_w + (size_t)l * Dm * 3 * Dm;
        const float* qb  = qkv_b + (size_t)l * 3 * Dm;
        const float* ow  = out_w + (size_t)l * Dm * Dm;
        const float* ob  = out_b + (size_t)l * Dm;
        const float* l2g = ln2_g + (size_t)l * Dm;
        const float* l2b = ln2_b + (size_t)l * Dm;
        const float* f1w = fc1_w + (size_t)l * Dm * 4 * Dm;
        const float* f1b = fc1_b + (size_t)l * 4 * Dm;
        const float* f2w = fc2_w + (size_t)l * 4 * Dm * Dm;
        const float* f2b = fc2_b + (size_t)l * Dm;

        // xn = LN1(h)
        ln_k<<<Tn, 256, 0, stream>>>(h, l1g, l1b, xn);
        // qkv = xn @ qw + qb
        gemm_k<false, 0><<<dim3((3 * Dm) / BN, Tn / BM), 256, 0, stream>>>(
            xn, qw, qb, nullptr, qkv, Tn, 3 * Dm, Dm);
        // wv = attention(qkv)
        attn_k<<<dim3(Tn, Hn), 256, 0, stream>>>(qkv, amask, wv);
        // h = h + wv @ ow + ob
        gemm_k<false, 0><<<dim3(Dm / BN, Tn / BM), 256, 0, stream>>>(
            wv, ow, ob, h, h, Tn, Dm, Dm);
        // xn = LN2(h)
        ln_k<<<Tn, 256, 0, stream>>>(h, l2g, l2b, xn);
        // ff1 = gelu(xn @ f1w + f1b)
        gemm_k<false, 1><<<dim3((4 * Dm) / BN, Tn / BM), 256, 0, stream>>>(
            xn, f1w, f1b, nullptr, ff1, Tn, 4 * Dm, Dm);
        // h = h + ff1 @ f2w + f2b
        gemm_k<false, 0><<<dim3(Dm / BN, Tn / BM), 256, 0, stream>>>(
            ff1, f2w, f2b, h, h, Tn, Dm, 4 * Dm);
    }

    // xn = LN_f(h)
    ln_k<<<Tn, 256, 0, stream>>>(h, lnf_g, lnf_b, xn);
    // logits = xn @ lm_w^T   (lm_w is V x D row-major -> BT)
    gemm_k<true, 0><<<dim3((Vn + BN - 1) / BN, Tn / BM), 256, 0, stream>>>(
        xn, lm_w, nullptr, nullptr, outf, Tn, Vn, Dm);
}

// Round 2
// 12143.781 us; speedup vs baseline: 2.4521x; 2.4521x over previous
//
#include <hip/hip_runtime.h>
#include <hip/hip_bf16.h>
#include <math.h>

// GPT-2 small forward: L=12, T=1024, D=1024, H=16, HD=64, V=50257, B=1
#define Lnum 12
#define Tn 1024
#define Dm 1024
#define Hn 16
#define HDn 64
#define Vn 50257

typedef __bf16 bf16;
typedef __bf16 bf16x8 __attribute__((ext_vector_type(8)));
typedef float f32x4 __attribute__((ext_vector_type(4)));

__device__ __forceinline__ void gload_lds16(const void* g, void* l) {
    __builtin_amdgcn_global_load_lds(
        (const __attribute__((address_space(1))) void*)g,
        (__attribute__((address_space(3))) void*)l, 16, 0, 0);
}

__device__ __forceinline__ float gelu_f(float x) {
    const float c = 0.7978845608028654f; // sqrt(2/pi)
    return 0.5f * x * (1.0f + tanhf(c * (x + 0.044715f * x * x * x)));
}

// ---------------- embedding ----------------
__global__ __launch_bounds__(256) void embed_k(const int* __restrict__ x,
                                               const float* __restrict__ tok,
                                               const float* __restrict__ pos,
                                               float* __restrict__ h) {
    int t = blockIdx.x;
    int id = x[t];
    const float* tr = tok + (size_t)id * Dm;
    const float* pr = pos + (size_t)t * Dm;
    float* hr = h + (size_t)t * Dm;
    for (int i = threadIdx.x; i < Dm; i += 256) hr[i] = tr[i] + pr[i];
}

// ---------------- layernorm (fp32 in, OT out) ----------------
template <typename OT>
__global__ __launch_bounds__(256) void ln_k(const float* __restrict__ x,
                                            const float* __restrict__ g,
                                            const float* __restrict__ b,
                                            OT* __restrict__ y) {
    int row = blockIdx.x;
    int tid = threadIdx.x;
    const float* xr = x + (size_t)row * Dm;
    float s = 0.f, s2 = 0.f;
    for (int i = tid; i < Dm; i += 256) { float v = xr[i]; s += v; s2 += v * v; }
    __shared__ float rs[256], rs2[256];
    rs[tid] = s; rs2[tid] = s2;
    __syncthreads();
    for (int off = 128; off; off >>= 1) {
        if (tid < off) { rs[tid] += rs[tid + off]; rs2[tid] += rs2[tid + off]; }
        __syncthreads();
    }
    float mean = rs[0] * (1.0f / Dm);
    float var = rs2[0] * (1.0f / Dm) - mean * mean;
    float inv = rsqrtf(var + 1e-5f);
    OT* yr = y + (size_t)row * Dm;
    for (int i = tid; i < Dm; i += 256) yr[i] = (OT)((xr[i] - mean) * inv * g[i] + b[i]);
}

// ---------------- fused per-layer weight transpose+convert ----------------
// W (K x N fp32, k-major) -> WT (N x K bf16, n-major)
__global__ __launch_bounds__(256) void tconv4_k(const float* __restrict__ qw,
                                                const float* __restrict__ ow,
                                                const float* __restrict__ f1,
                                                const float* __restrict__ f2,
                                                bf16* __restrict__ qT, bf16* __restrict__ oT,
                                                bf16* __restrict__ f1T, bf16* __restrict__ f2T) {
    int blk = blockIdx.x;
    const float* W; bf16* WT; int K, N, bi;
    if (blk < 3072)      { W = qw; WT = qT;  K = 1024; N = 3072; bi = blk; }
    else if (blk < 4096) { W = ow; WT = oT;  K = 1024; N = 1024; bi = blk - 3072; }
    else if (blk < 8192) { W = f1; WT = f1T; K = 1024; N = 4096; bi = blk - 4096; }
    else                 { W = f2; WT = f2T; K = 4096; N = 1024; bi = blk - 8192; }
    int nx = N >> 5;
    int n0 = (bi % nx) * 32;
    int k0 = (bi / nx) * 32;
    __shared__ float t[32][33];
    int tx = threadIdx.x & 31, ty = threadIdx.x >> 5;   // 32 x 8
#pragma unroll
    for (int r = 0; r < 4; ++r)
        t[ty + r * 8][tx] = W[(size_t)(k0 + ty + r * 8) * N + n0 + tx];
    __syncthreads();
#pragma unroll
    for (int r = 0; r < 4; ++r)
        WT[(size_t)(n0 + ty + r * 8) * K + k0 + tx] = (bf16)t[tx][ty + r * 8];
}

// ---------------- MFMA GEMM: C[M,N] = act(A @ Bt^T + bias) (+resid) ----------
// A: M x K bf16 row-major. Bt: N x K row-major (B transposed).
// BMODE 0: Bt is bf16 (global_load_lds).  BMODE 1: Bt is fp32 (reg-stage+cvt).
#define GBM 128
#define GBN 128
#define GBK 32

template <int ACT, bool RESID, bool OUTBF, int BMODE, bool NTAIL>
__global__ __launch_bounds__(256) void mgemm_k(const bf16* __restrict__ A,
                                               const void* __restrict__ Btv,
                                               const float* __restrict__ bias,
                                               const float* __restrict__ resid,
                                               void* __restrict__ Cv,
                                               int N, int K) {
    __shared__ bf16 As[GBM * GBK];
    __shared__ bf16 Bs[GBN * GBK];
    const int tid = threadIdx.x;
    const int lane = tid & 63;
    const int wid = tid >> 6;
    const int bm = blockIdx.x * GBM;   // x = row-block (8 co-resident blocks share B panel)
    const int bn = blockIdx.y * GBN;
    const int wr = (wid >> 1) * 64;
    const int wc = (wid & 1) * 64;
    const int l15 = lane & 15;
    const int l4 = lane >> 4;

    f32x4 acc[4][4] = {};

    const int ch = wid * 64 + lane;          // 0..255
    const int ar = ch >> 2;                  // staging row (it=0)
    const int ac = (ch & 3) * 8;             // staging k-elem offset

    for (int k0 = 0; k0 < K; k0 += GBK) {
        // ---- stage A (128x32 bf16) via global_load_lds ----
        gload_lds16(A + (size_t)(bm + ar) * K + k0 + ac, &As[wid * 512]);
        gload_lds16(A + (size_t)(bm + 64 + ar) * K + k0 + ac, &As[2048 + wid * 512]);
        if (BMODE == 0) {
            const bf16* B = (const bf16*)Btv;
            gload_lds16(B + (size_t)(bn + ar) * K + k0 + ac, &Bs[wid * 512]);
            gload_lds16(B + (size_t)(bn + 64 + ar) * K + k0 + ac, &Bs[2048 + wid * 512]);
        } else {
            const float* B = (const float*)Btv;
#pragma unroll
            for (int it = 0; it < 2; ++it) {
                int gi = it * 256 + tid;
                int n = bn + (gi >> 2);
                if (NTAIL && n >= N) n = N - 1;
                const float* g = B + (size_t)n * K + k0 + (gi & 3) * 8;
                float4 f0 = *(const float4*)g;
                float4 f1 = *(const float4*)(g + 4);
                bf16x8 pk;
                pk[0] = (bf16)f0.x; pk[1] = (bf16)f0.y; pk[2] = (bf16)f0.z; pk[3] = (bf16)f0.w;
                pk[4] = (bf16)f1.x; pk[5] = (bf16)f1.y; pk[6] = (bf16)f1.z; pk[7] = (bf16)f1.w;
                *(bf16x8*)&Bs[gi * 8] = pk;
            }
        }
        __syncthreads();

        bf16x8 a[4], b[4];
        const int ko = l4 * 8;
#pragma unroll
        for (int i = 0; i < 4; ++i)
            a[i] = *(const bf16x8*)&As[(wr + i * 16 + l15) * GBK + ko];
#pragma unroll
        for (int j = 0; j < 4; ++j)
            b[j] = *(const bf16x8*)&Bs[(wc + j * 16 + l15) * GBK + ko];
#pragma unroll
        for (int i = 0; i < 4; ++i)
#pragma unroll
            for (int j = 0; j < 4; ++j)
                acc[i][j] = __builtin_amdgcn_mfma_f32_16x16x32_bf16(a[i], b[j], acc[i][j], 0, 0, 0);
        __syncthreads();
    }

    // ---- epilogue ----
#pragma unroll
    for (int i = 0; i < 4; ++i) {
        int row0 = bm + wr + i * 16 + l4 * 4;
#pragma unroll
        for (int j = 0; j < 4; ++j) {
            int col = bn + wc + j * 16 + l15;
            if (NTAIL && col >= N) continue;
            float bv = bias ? bias[col] : 0.f;
#pragma unroll
            for (int r = 0; r < 4; ++r) {
                float v = acc[i][j][r] + bv;
                if (ACT == 1) v = gelu_f(v);
                size_t idx = (size_t)(row0 + r) * N + col;
                if (RESID) v += resid[idx];
                if (OUTBF) ((bf16*)Cv)[idx] = (bf16)v;
                else       ((float*)Cv)[idx] = v;
            }
        }
    }
}

// ---------------- attention (fp32, one block per (query t, head h)) --------
__global__ __launch_bounds__(256) void attn_k(const float* __restrict__ qkv,
                                              const float* __restrict__ amask,
                                              bf16* __restrict__ out) {
    int t = blockIdx.x;
    int hh = blockIdx.y;
    int tid = threadIdx.x;
    __shared__ float q[HDn];
    __shared__ float s[Tn];
    __shared__ float red[256];
    __shared__ float part[4][HDn];

    const float* qrow = qkv + (size_t)t * (3 * Dm) + hh * HDn;
    if (tid < HDn) q[tid] = qrow[tid];
    __syncthreads();

    int nk = t + 1;
    for (int k = tid; k < nk; k += 256) {
        const float* krow = qkv + (size_t)k * (3 * Dm) + Dm + hh * HDn;
        float d = 0.f;
#pragma unroll
        for (int i = 0; i < HDn; ++i) d += q[i] * krow[i];
        d *= 0.125f;
        d += (1.0f - amask[k]) * -1e30f;
        s[k] = d;
    }
    __syncthreads();

    float m = -INFINITY;
    for (int k = tid; k < nk; k += 256) m = fmaxf(m, s[k]);
    red[tid] = m;
    __syncthreads();
    for (int off = 128; off; off >>= 1) {
        if (tid < off) red[tid] = fmaxf(red[tid], red[tid + off]);
        __syncthreads();
    }
    m = red[0];
    __syncthreads();

    float sum = 0.f;
    for (int k = tid; k < nk; k += 256) { float e = expf(s[k] - m); s[k] = e; sum += e; }
    red[tid] = sum;
    __syncthreads();
    for (int off = 128; off; off >>= 1) {
        if (tid < off) red[tid] += red[tid + off];
        __syncthreads();
    }
    float inv = 1.0f / red[0];
    __syncthreads();

    int d = tid & 63;
    int g = tid >> 6;
    float acc = 0.f;
    for (int k = g; k < nk; k += 4)
        acc += s[k] * qkv[(size_t)k * (3 * Dm) + 2 * Dm + hh * HDn + d];
    part[g][d] = acc;
    __syncthreads();
    if (tid < HDn) {
        float v = (part[0][tid] + part[1][tid] + part[2][tid] + part[3][tid]) * inv;
        out[(size_t)t * Dm + hh * HDn + tid] = (bf16)v;
    }
}

// ---------------- launch ----------------
extern "C" void kernel_launch(void* const* d_in, const int* in_sizes, int n_in,
                              void* d_out, int out_size, void* d_ws, size_t ws_size,
                              hipStream_t stream) {
    const int*   x      = (const int*)d_in[0];
    const float* amask  = (const float*)d_in[1];
    const float* tok    = (const float*)d_in[2];
    const float* pos    = (const float*)d_in[3];
    const float* ln1_g  = (const float*)d_in[4];
    const float* ln1_b  = (const float*)d_in[5];
    const float* qkv_w  = (const float*)d_in[6];
    const float* qkv_b  = (const float*)d_in[7];
    const float* out_w  = (const float*)d_in[8];
    const float* out_b  = (const float*)d_in[9];
    const float* ln2_g  = (const float*)d_in[10];
    const float* ln2_b  = (const float*)d_in[11];
    const float* fc1_w  = (const float*)d_in[12];
    const float* fc1_b  = (const float*)d_in[13];
    const float* fc2_w  = (const float*)d_in[14];
    const float* fc2_b  = (const float*)d_in[15];
    const float* lnf_g  = (const float*)d_in[16];
    const float* lnf_b  = (const float*)d_in[17];
    const float* lm_w   = (const float*)d_in[18];

    char* ws = (char*)d_ws;
    float* h      = (float*)(ws + 0);                       // 4 MB
    float* qkv    = (float*)(ws + (4u << 20));              // 12 MB
    bf16*  xn_bf  = (bf16*) (ws + (16u << 20));             // 2 MB
    bf16*  wv_bf  = (bf16*) (ws + (18u << 20));             // 2 MB
    bf16*  ff1_bf = (bf16*) (ws + (20u << 20));             // 8 MB
    bf16*  Wbuf   = (bf16*) (ws + (28u << 20));             // 24 MB
    bf16* qT  = Wbuf;                  // 3072 x 1024
    bf16* oT  = qT  + 3145728;         // 1024 x 1024
    bf16* f1T = oT  + 1048576;         // 4096 x 1024
    bf16* f2T = f1T + 4194304;         // 1024 x 4096
    float* outf = (float*)d_out;

    embed_k<<<Tn, 256, 0, stream>>>(x, tok, pos, h);

    for (int l = 0; l < Lnum; ++l) {
        const float* l1g = ln1_g + (size_t)l * Dm;
        const float* l1b = ln1_b + (size_t)l * Dm;
        const float* qw  = qkv_w + (size_t)l * Dm * 3 * Dm;
        const float* qb  = qkv_b + (size_t)l * 3 * Dm;
        const float* ow  = out_w + (size_t)l * Dm * Dm;
        const float* ob  = out_b + (size_t)l * Dm;
        const float* l2g = ln2_g + (size_t)l * Dm;
        const float* l2b = ln2_b + (size_t)l * Dm;
        const float* f1w = fc1_w + (size_t)l * Dm * 4 * Dm;
        const float* f1b = fc1_b + (size_t)l * 4 * Dm;
        const float* f2w = fc2_w + (size_t)l * 4 * Dm * Dm;
        const float* f2b = fc2_b + (size_t)l * Dm;

        // weights -> bf16 transposed (N x K)
        tconv4_k<<<12288, 256, 0, stream>>>(qw, ow, f1w, f2w, qT, oT, f1T, f2T);
        // xn = LN1(h)  (bf16)
        ln_k<bf16><<<Tn, 256, 0, stream>>>(h, l1g, l1b, xn_bf);
        // qkv = xn @ qw + qb   (fp32 out, for fp32 attention)
        mgemm_k<0, false, false, 0, false><<<dim3(8, 24), 256, 0, stream>>>(
            xn_bf, qT, qb, nullptr, qkv, 3 * Dm, Dm);
        // wv = attention(qkv)  (bf16 out)
        attn_k<<<dim3(Tn, Hn), 256, 0, stream>>>(qkv, amask, wv_bf);
        // h = h + wv @ ow + ob
        mgemm_k<0, true, false, 0, false><<<dim3(8, 8), 256, 0, stream>>>(
            wv_bf, oT, ob, h, h, Dm, Dm);
        // xn = LN2(h)
        ln_k<bf16><<<Tn, 256, 0, stream>>>(h, l2g, l2b, xn_bf);
        // ff1 = gelu(xn @ f1w + f1b)  (bf16 out)
        mgemm_k<1, false, true, 0, false><<<dim3(8, 32), 256, 0, stream>>>(
            xn_bf, f1T, f1b, nullptr, ff1_bf, 4 * Dm, Dm);
        // h = h + ff1 @ f2w + f2b
        mgemm_k<0, true, false, 0, false><<<dim3(8, 8), 256, 0, stream>>>(
            ff1_bf, f2T, f2b, h, h, Dm, 4 * Dm);
    }

    // xn = LN_f(h)
    ln_k<bf16><<<Tn, 256, 0, stream>>>(h, lnf_g, lnf_b, xn_bf);
    // logits = xn @ lm_w^T  (lm_w already N x K, fp32 reg-staged)
    mgemm_k<0, false, false, 1, true><<<dim3(8, (Vn + GBN - 1) / GBN), 256, 0, stream>>>(
        xn_bf, lm_w, nullptr, nullptr, outf, Vn, Dm);
}

// Round 5
// 3244.791 us; speedup vs baseline: 9.1772x; 3.7425x over previous
//
#include <hip/hip_runtime.h>
#include <hip/hip_bf16.h>
#include <math.h>

// GPT-2 small forward: L=12, T=1024, D=1024, H=16, HD=64, V=50257, B=1
#define Lnum 12
#define Tn 1024
#define Dm 1024
#define Hn 16
#define HDn 64
#define Vn 50257

typedef __bf16 bf16;
typedef __bf16 bf16x4 __attribute__((ext_vector_type(4)));
typedef __bf16 bf16x8 __attribute__((ext_vector_type(8)));
typedef float f32x4 __attribute__((ext_vector_type(4)));

__device__ __forceinline__ void gload_lds16(const void* g, void* l) {
    __builtin_amdgcn_global_load_lds(
        (const __attribute__((address_space(1))) void*)g,
        (__attribute__((address_space(3))) void*)l, 16, 0, 0);
}

__device__ __forceinline__ float gelu_f(float x) {
    const float c = 0.7978845608028654f; // sqrt(2/pi)
    return 0.5f * x * (1.0f + tanhf(c * (x + 0.044715f * x * x * x)));
}

// ---------------- embedding ----------------
__global__ __launch_bounds__(256) void embed_k(const int* __restrict__ x,
                                               const float* __restrict__ tok,
                                               const float* __restrict__ pos,
                                               float* __restrict__ h) {
    int t = blockIdx.x;
    int id = x[t];
    const float* tr = tok + (size_t)id * Dm;
    const float* pr = pos + (size_t)t * Dm;
    float* hr = h + (size_t)t * Dm;
    for (int i = threadIdx.x; i < Dm; i += 256) hr[i] = tr[i] + pr[i];
}

// ---------------- layernorm (fp32 in, OT out) ----------------
template <typename OT>
__global__ __launch_bounds__(256) void ln_k(const float* __restrict__ x,
                                            const float* __restrict__ g,
                                            const float* __restrict__ b,
                                            OT* __restrict__ y) {
    int row = blockIdx.x;
    int tid = threadIdx.x;
    const float* xr = x + (size_t)row * Dm;
    float s = 0.f, s2 = 0.f;
    for (int i = tid; i < Dm; i += 256) { float v = xr[i]; s += v; s2 += v * v; }
    __shared__ float rs[256], rs2[256];
    rs[tid] = s; rs2[tid] = s2;
    __syncthreads();
    for (int off = 128; off; off >>= 1) {
        if (tid < off) { rs[tid] += rs[tid + off]; rs2[tid] += rs2[tid + off]; }
        __syncthreads();
    }
    float mean = rs[0] * (1.0f / Dm);
    float var = rs2[0] * (1.0f / Dm) - mean * mean;
    float inv = rsqrtf(var + 1e-5f);
    OT* yr = y + (size_t)row * Dm;
    for (int i = tid; i < Dm; i += 256) yr[i] = (OT)((xr[i] - mean) * inv * g[i] + b[i]);
}

// ---------------- fused per-layer weight transpose+convert ----------------
__global__ __launch_bounds__(256) void tconv4_k(const float* __restrict__ qw,
                                                const float* __restrict__ ow,
                                                const float* __restrict__ f1,
                                                const float* __restrict__ f2,
                                                bf16* __restrict__ qT, bf16* __restrict__ oT,
                                                bf16* __restrict__ f1T, bf16* __restrict__ f2T) {
    int blk = blockIdx.x;
    const float* W; bf16* WT; int K, N, bi;
    if (blk < 3072)      { W = qw; WT = qT;  K = 1024; N = 3072; bi = blk; }
    else if (blk < 4096) { W = ow; WT = oT;  K = 1024; N = 1024; bi = blk - 3072; }
    else if (blk < 8192) { W = f1; WT = f1T; K = 1024; N = 4096; bi = blk - 4096; }
    else                 { W = f2; WT = f2T; K = 4096; N = 1024; bi = blk - 8192; }
    int nx = N >> 5;
    int n0 = (bi % nx) * 32;
    int k0 = (bi / nx) * 32;
    __shared__ float t[32][33];
    int tx = threadIdx.x & 31, ty = threadIdx.x >> 5;   // 32 x 8
#pragma unroll
    for (int r = 0; r < 4; ++r)
        t[ty + r * 8][tx] = W[(size_t)(k0 + ty + r * 8) * N + n0 + tx];
    __syncthreads();
#pragma unroll
    for (int r = 0; r < 4; ++r)
        WT[(size_t)(n0 + ty + r * 8) * K + k0 + tx] = (bf16)t[tx][ty + r * 8];
}

// ---------------- MFMA GEMM ----------
#define GBM 128
#define GBN 128
#define GBK 32

template <int ACT, bool RESID, bool OUTBF, int BMODE, bool NTAIL>
__global__ __launch_bounds__(256) void mgemm_k(const bf16* __restrict__ A,
                                               const void* __restrict__ Btv,
                                               const float* __restrict__ bias,
                                               const float* __restrict__ resid,
                                               void* __restrict__ Cv,
                                               int N, int K) {
    __shared__ bf16 As[GBM * GBK];
    __shared__ bf16 Bs[GBN * GBK];
    const int tid = threadIdx.x;
    const int lane = tid & 63;
    const int wid = tid >> 6;
    const int bm = blockIdx.x * GBM;
    const int bn = blockIdx.y * GBN;
    const int wr = (wid >> 1) * 64;
    const int wc = (wid & 1) * 64;
    const int l15 = lane & 15;
    const int l4 = lane >> 4;

    f32x4 acc[4][4] = {};

    const int ch = wid * 64 + lane;
    const int ar = ch >> 2;
    const int ac = (ch & 3) * 8;

    for (int k0 = 0; k0 < K; k0 += GBK) {
        gload_lds16(A + (size_t)(bm + ar) * K + k0 + ac, &As[wid * 512]);
        gload_lds16(A + (size_t)(bm + 64 + ar) * K + k0 + ac, &As[2048 + wid * 512]);
        if (BMODE == 0) {
            const bf16* B = (const bf16*)Btv;
            gload_lds16(B + (size_t)(bn + ar) * K + k0 + ac, &Bs[wid * 512]);
            gload_lds16(B + (size_t)(bn + 64 + ar) * K + k0 + ac, &Bs[2048 + wid * 512]);
        } else {
            const float* B = (const float*)Btv;
#pragma unroll
            for (int it = 0; it < 2; ++it) {
                int gi = it * 256 + tid;
                int n = bn + (gi >> 2);
                if (NTAIL && n >= N) n = N - 1;
                const float* g = B + (size_t)n * K + k0 + (gi & 3) * 8;
                float4 f0 = *(const float4*)g;
                float4 f1 = *(const float4*)(g + 4);
                bf16x8 pk;
                pk[0] = (bf16)f0.x; pk[1] = (bf16)f0.y; pk[2] = (bf16)f0.z; pk[3] = (bf16)f0.w;
                pk[4] = (bf16)f1.x; pk[5] = (bf16)f1.y; pk[6] = (bf16)f1.z; pk[7] = (bf16)f1.w;
                *(bf16x8*)&Bs[gi * 8] = pk;
            }
        }
        __syncthreads();

        bf16x8 a[4], b[4];
        const int ko = l4 * 8;
#pragma unroll
        for (int i = 0; i < 4; ++i)
            a[i] = *(const bf16x8*)&As[(wr + i * 16 + l15) * GBK + ko];
#pragma unroll
        for (int j = 0; j < 4; ++j)
            b[j] = *(const bf16x8*)&Bs[(wc + j * 16 + l15) * GBK + ko];
#pragma unroll
        for (int i = 0; i < 4; ++i)
#pragma unroll
            for (int j = 0; j < 4; ++j)
                acc[i][j] = __builtin_amdgcn_mfma_f32_16x16x32_bf16(a[i], b[j], acc[i][j], 0, 0, 0);
        __syncthreads();
    }

#pragma unroll
    for (int i = 0; i < 4; ++i) {
        int row0 = bm + wr + i * 16 + l4 * 4;
#pragma unroll
        for (int j = 0; j < 4; ++j) {
            int col = bn + wc + j * 16 + l15;
            if (NTAIL && col >= N) continue;
            float bv = bias ? bias[col] : 0.f;
#pragma unroll
            for (int r = 0; r < 4; ++r) {
                float v = acc[i][j][r] + bv;
                if (ACT == 1) v = gelu_f(v);
                size_t idx = (size_t)(row0 + r) * N + col;
                if (RESID) v += resid[idx];
                if (OUTBF) ((bf16*)Cv)[idx] = (bf16)v;
                else       ((float*)Cv)[idx] = v;
            }
        }
    }
}

// ---------------- MFMA flash attention ----------------
// qkv: [T][3D] bf16. Grid (qt=T/64, h). Block 256 = 4 waves, wave owns 16 q-rows.
// Swapped QK^T (S^T = K·Q^T) so softmax per q is lane-local + 2 shuffles.
__global__ __launch_bounds__(256) void fattn_k(const bf16* __restrict__ qkv,
                                               const float* __restrict__ amask,
                                               bf16* __restrict__ out) {
    __shared__ bf16 Ks[64 * 64];      // [kr][d], rows 128B, XOR-swizzled
    __shared__ bf16 Vt[64 * 64];      // [d][k], rows 128B, XOR-swizzled
    __shared__ bf16 Pw[4][16 * 64];   // per-wave P [q][k], XOR-swizzled
    __shared__ float addb[Tn];        // attention-mask additive bias
    __shared__ float bcast[4][16];    // per-wave row-stat broadcast

    const int qt = blockIdx.x;
    const int hh = blockIdx.y;
    const int tid = threadIdx.x;
    const int lane = tid & 63;
    const int wq = tid >> 6;
    const int l15 = lane & 15;
    const int g = lane >> 4;

    const int qglob = qt * 64 + wq * 16 + l15;
    const int nkt = qt + 1;
    const int kmax = nkt * 64;

    for (int i = tid; i < kmax; i += 256)
        addb[i] = (1.0f - amask[i]) * -3.0e38f;

    // Q fragments in registers (row qglob, cols h*64 + s*32 + g*8)
    bf16x8 qreg[2];
    {
        const bf16* qp = qkv + (size_t)qglob * (3 * Dm) + hh * HDn + g * 8;
        qreg[0] = *(const bf16x8*)qp;
        qreg[1] = *(const bf16x8*)(qp + 32);
    }

    f32x4 accO[4] = {};               // O[q=4g+r][d=16nf+l15]
    float mrun = -3.0e38f, lrun = 0.f;

    for (int kt = 0; kt < nkt; ++kt) {
        const int kb = kt * 64;
        __syncthreads();   // previous tile fully consumed
        // ---- stage K tile [64][64]: 512 x 16B chunks (FULL coverage) ----
#pragma unroll
        for (int t2 = 0; t2 < 2; ++t2) {
            int c = tid + t2 * 256;
            int kr = c >> 3;             // 0..63
            int d8 = (c & 7) * 8;        // 0..56
            const bf16* gp = qkv + (size_t)(kb + kr) * (3 * Dm) + Dm + hh * HDn + d8;
            bf16x8 v = *(const bf16x8*)gp;
            *(bf16x8*)((char*)Ks + kr * 128 + ((d8 * 2) ^ ((kr & 7) << 4))) = v;
        }
        // ---- stage V transposed: Vt[d][k] ----
#pragma unroll
        for (int t2 = 0; t2 < 2; ++t2) {
            int c = tid + t2 * 256;
            int k = c >> 3, d0 = (c & 7) * 8;
            const bf16* gp = qkv + (size_t)(kb + k) * (3 * Dm) + 2 * Dm + hh * HDn + d0;
            bf16x8 v = *(const bf16x8*)gp;
#pragma unroll
            for (int j = 0; j < 8; ++j) {
                int d = d0 + j;
                *(bf16*)((char*)Vt + d * 128 + ((2 * k) ^ ((d & 7) << 4))) = v[j];
            }
        }
        __syncthreads();

        // ---- S^T = K · Q^T ----
        f32x4 accS[4] = {};
#pragma unroll
        for (int s = 0; s < 2; ++s)
#pragma unroll
            for (int mf = 0; mf < 4; ++mf) {
                int kr = mf * 16 + l15;
                bf16x8 af = *(const bf16x8*)((char*)Ks + kr * 128 + ((s * 64 + g * 16) ^ ((kr & 7) << 4)));
                accS[mf] = __builtin_amdgcn_mfma_f32_16x16x32_bf16(af, qreg[s], accS[mf], 0, 0, 0);
            }

        // ---- online softmax (stats per q = l15) ----
        float p[16];
        float tmax = -3.0e38f;
#pragma unroll
        for (int mf = 0; mf < 4; ++mf)
#pragma unroll
            for (int r = 0; r < 4; ++r) {
                int k = kb + mf * 16 + g * 4 + r;
                float sv = accS[mf][r] * 0.125f + addb[k];
                if (k > qglob) sv = -3.0e38f;     // causal
                p[mf * 4 + r] = sv;
                tmax = fmaxf(tmax, sv);
            }
        tmax = fmaxf(tmax, __shfl_xor(tmax, 16, 64));
        tmax = fmaxf(tmax, __shfl_xor(tmax, 32, 64));
        float mnew = fmaxf(mrun, tmax);
        float alpha = expf(mrun - mnew);
        float psum = 0.f;
#pragma unroll
        for (int i = 0; i < 16; ++i) { float e = expf(p[i] - mnew); p[i] = e; psum += e; }
        psum += __shfl_xor(psum, 16, 64);
        psum += __shfl_xor(psum, 32, 64);
        lrun = lrun * alpha + psum;
        mrun = mnew;

        // rescale O by alpha (per q-row broadcast via LDS, same-wave in-order DS)
        if (g == 0) bcast[wq][l15] = alpha;
        f32x4 av = *(f32x4*)&bcast[wq][g * 4];
#pragma unroll
        for (int nf = 0; nf < 4; ++nf)
#pragma unroll
            for (int r = 0; r < 4; ++r) accO[nf][r] *= av[r];

        // ---- P (bf16) -> per-wave LDS, re-read as PV A-fragments ----
        char* pw = (char*)Pw[wq];
#pragma unroll
        for (int mf = 0; mf < 4; ++mf) {
            bf16x4 pk;
            pk[0] = (bf16)p[mf * 4 + 0]; pk[1] = (bf16)p[mf * 4 + 1];
            pk[2] = (bf16)p[mf * 4 + 2]; pk[3] = (bf16)p[mf * 4 + 3];
            *(bf16x4*)(pw + l15 * 128 + ((32 * mf + 8 * g) ^ ((l15 & 7) << 4))) = pk;
        }
        bf16x8 pa[2];
#pragma unroll
        for (int s = 0; s < 2; ++s)
            pa[s] = *(const bf16x8*)(pw + l15 * 128 + ((s * 64 + g * 16) ^ ((l15 & 7) << 4)));

        // ---- O += P · V ----
#pragma unroll
        for (int s = 0; s < 2; ++s)
#pragma unroll
            for (int nf = 0; nf < 4; ++nf) {
                int d = nf * 16 + l15;
                bf16x8 bfg = *(const bf16x8*)((char*)Vt + d * 128 + ((s * 64 + g * 16) ^ ((d & 7) << 4)));
                accO[nf] = __builtin_amdgcn_mfma_f32_16x16x32_bf16(pa[s], bfg, accO[nf], 0, 0, 0);
            }
    }

    // ---- epilogue: O /= l, write bf16 ----
    if (g == 0) bcast[wq][l15] = 1.0f / lrun;
    f32x4 lv = *(f32x4*)&bcast[wq][g * 4];
#pragma unroll
    for (int nf = 0; nf < 4; ++nf)
#pragma unroll
        for (int r = 0; r < 4; ++r) {
            int row = qt * 64 + wq * 16 + 4 * g + r;
            int col = hh * HDn + nf * 16 + l15;
            out[(size_t)row * Dm + col] = (bf16)(accO[nf][r] * lv[r]);
        }
}

// ---------------- launch ----------------
extern "C" void kernel_launch(void* const* d_in, const int* in_sizes, int n_in,
                              void* d_out, int out_size, void* d_ws, size_t ws_size,
                              hipStream_t stream) {
    const int*   x      = (const int*)d_in[0];
    const float* amask  = (const float*)d_in[1];
    const float* tok    = (const float*)d_in[2];
    const float* pos    = (const float*)d_in[3];
    const float* ln1_g  = (const float*)d_in[4];
    const float* ln1_b  = (const float*)d_in[5];
    const float* qkv_w  = (const float*)d_in[6];
    const float* qkv_b  = (const float*)d_in[7];
    const float* out_w  = (const float*)d_in[8];
    const float* out_b  = (const float*)d_in[9];
    const float* ln2_g  = (const float*)d_in[10];
    const float* ln2_b  = (const float*)d_in[11];
    const float* fc1_w  = (const float*)d_in[12];
    const float* fc1_b  = (const float*)d_in[13];
    const float* fc2_w  = (const float*)d_in[14];
    const float* fc2_b  = (const float*)d_in[15];
    const float* lnf_g  = (const float*)d_in[16];
    const float* lnf_b  = (const float*)d_in[17];
    const float* lm_w   = (const float*)d_in[18];

    char* ws = (char*)d_ws;
    float* h      = (float*)(ws + 0);                       // 4 MB
    bf16*  qkv_bf = (bf16*) (ws + (4u << 20));              // 6 MB
    bf16*  xn_bf  = (bf16*) (ws + (16u << 20));             // 2 MB
    bf16*  wv_bf  = (bf16*) (ws + (18u << 20));             // 2 MB
    bf16*  ff1_bf = (bf16*) (ws + (20u << 20));             // 8 MB
    bf16*  Wbuf   = (bf16*) (ws + (28u << 20));             // 24 MB
    bf16* qT  = Wbuf;
    bf16* oT  = qT  + 3145728;
    bf16* f1T = oT  + 1048576;
    bf16* f2T = f1T + 4194304;
    float* outf = (float*)d_out;

    embed_k<<<Tn, 256, 0, stream>>>(x, tok, pos, h);

    for (int l = 0; l < Lnum; ++l) {
        const float* l1g = ln1_g + (size_t)l * Dm;
        const float* l1b = ln1_b + (size_t)l * Dm;
        const float* qw  = qkv_w + (size_t)l * Dm * 3 * Dm;
        const float* qb  = qkv_b + (size_t)l * 3 * Dm;
        const float* ow  = out_w + (size_t)l * Dm * Dm;
        const float* ob  = out_b + (size_t)l * Dm;
        const float* l2g = ln2_g + (size_t)l * Dm;
        const float* l2b = ln2_b + (size_t)l * Dm;
        const float* f1w = fc1_w + (size_t)l * Dm * 4 * Dm;
        const float* f1b = fc1_b + (size_t)l * 4 * Dm;
        const float* f2w = fc2_w + (size_t)l * 4 * Dm * Dm;
        const float* f2b = fc2_b + (size_t)l * Dm;

        tconv4_k<<<12288, 256, 0, stream>>>(qw, ow, f1w, f2w, qT, oT, f1T, f2T);
        ln_k<bf16><<<Tn, 256, 0, stream>>>(h, l1g, l1b, xn_bf);
        // qkv (bf16 out)
        mgemm_k<0, false, true, 0, false><<<dim3(8, 24), 256, 0, stream>>>(
            xn_bf, qT, qb, nullptr, qkv_bf, 3 * Dm, Dm);
        // flash attention
        fattn_k<<<dim3(Tn / 64, Hn), 256, 0, stream>>>(qkv_bf, amask, wv_bf);
        // h = h + wv @ ow + ob
        mgemm_k<0, true, false, 0, false><<<dim3(8, 8), 256, 0, stream>>>(
            wv_bf, oT, ob, h, h, Dm, Dm);
        ln_k<bf16><<<Tn, 256, 0, stream>>>(h, l2g, l2b, xn_bf);
        mgemm_k<1, false, true, 0, false><<<dim3(8, 32), 256, 0, stream>>>(
            xn_bf, f1T, f1b, nullptr, ff1_bf, 4 * Dm, Dm);
        mgemm_k<0, true, false, 0, false><<<dim3(8, 8), 256, 0, stream>>>(
            ff1_bf, f2T, f2b, h, h, Dm, 4 * Dm);
    }

    ln_k<bf16><<<Tn, 256, 0, stream>>>(h, lnf_g, lnf_b, xn_bf);
    mgemm_k<0, false, false, 1, true><<<dim3(8, (Vn + GBN - 1) / GBN), 256, 0, stream>>>(
        xn_bf, lm_w, nullptr, nullptr, outf, Vn, Dm);
}

// Round 6
// 2528.221 us; speedup vs baseline: 11.7782x; 1.2834x over previous
//
#include <hip/hip_runtime.h>
#include <hip/hip_bf16.h>
#include <math.h>

// GPT-2 small forward: L=12, T=1024, D=1024, H=16, HD=64, V=50257, B=1
#define Lnum 12
#define Tn 1024
#define Dm 1024
#define Hn 16
#define HDn 64
#define Vn 50257

typedef __bf16 bf16;
typedef __bf16 bf16x4 __attribute__((ext_vector_type(4)));
typedef __bf16 bf16x8 __attribute__((ext_vector_type(8)));
typedef float f32x4 __attribute__((ext_vector_type(4)));

__device__ __forceinline__ void gload_lds16(const void* g, void* l) {
    __builtin_amdgcn_global_load_lds(
        (const __attribute__((address_space(1))) void*)g,
        (__attribute__((address_space(3))) void*)l, 16, 0, 0);
}

__device__ __forceinline__ float gelu_f(float x) {
    const float c = 0.7978845608028654f; // sqrt(2/pi)
    return 0.5f * x * (1.0f + tanhf(c * (x + 0.044715f * x * x * x)));
}

// ---------------- embedding (float4) ----------------
__global__ __launch_bounds__(256) void embed_k(const int* __restrict__ x,
                                               const float* __restrict__ tok,
                                               const float* __restrict__ pos,
                                               float* __restrict__ h) {
    int t = blockIdx.x;
    int id = x[t];
    const float4* tr = (const float4*)(tok + (size_t)id * Dm);
    const float4* pr = (const float4*)(pos + (size_t)t * Dm);
    float4* hr = (float4*)(h + (size_t)t * Dm);
    int i = threadIdx.x;
    float4 a = tr[i], b = pr[i];
    hr[i] = make_float4(a.x + b.x, a.y + b.y, a.z + b.z, a.w + b.w);
}

// ---------------- layernorm (fp32 in, bf16 out, float4 loads) ----------------
__global__ __launch_bounds__(256) void ln_k(const float* __restrict__ x,
                                            const float* __restrict__ g,
                                            const float* __restrict__ b,
                                            bf16* __restrict__ y) {
    int row = blockIdx.x;
    int tid = threadIdx.x;
    const float* xr = x + (size_t)row * Dm;
    float4 v = ((const float4*)xr)[tid];
    float s = v.x + v.y + v.z + v.w;
    float s2 = v.x * v.x + v.y * v.y + v.z * v.z + v.w * v.w;
    __shared__ float rs[256], rs2[256];
    rs[tid] = s; rs2[tid] = s2;
    __syncthreads();
    for (int off = 128; off; off >>= 1) {
        if (tid < off) { rs[tid] += rs[tid + off]; rs2[tid] += rs2[tid + off]; }
        __syncthreads();
    }
    float mean = rs[0] * (1.0f / Dm);
    float var = rs2[0] * (1.0f / Dm) - mean * mean;
    float inv = rsqrtf(var + 1e-5f);
    float4 gg = ((const float4*)g)[tid];
    float4 bb = ((const float4*)b)[tid];
    bf16x4 pk;
    pk[0] = (bf16)((v.x - mean) * inv * gg.x + bb.x);
    pk[1] = (bf16)((v.y - mean) * inv * gg.y + bb.y);
    pk[2] = (bf16)((v.z - mean) * inv * gg.z + bb.z);
    pk[3] = (bf16)((v.w - mean) * inv * gg.w + bb.w);
    *(bf16x4*)(y + (size_t)row * Dm + tid * 4) = pk;
}

// ---------------- fused per-layer weight transpose+convert ----------------
__global__ __launch_bounds__(256) void tconv4_k(const float* __restrict__ qw,
                                                const float* __restrict__ ow,
                                                const float* __restrict__ f1,
                                                const float* __restrict__ f2,
                                                bf16* __restrict__ qT, bf16* __restrict__ oT,
                                                bf16* __restrict__ f1T, bf16* __restrict__ f2T) {
    int blk = blockIdx.x;
    const float* W; bf16* WT; int K, N, bi;
    if (blk < 3072)      { W = qw; WT = qT;  K = 1024; N = 3072; bi = blk; }
    else if (blk < 4096) { W = ow; WT = oT;  K = 1024; N = 1024; bi = blk - 3072; }
    else if (blk < 8192) { W = f1; WT = f1T; K = 1024; N = 4096; bi = blk - 4096; }
    else                 { W = f2; WT = f2T; K = 4096; N = 1024; bi = blk - 8192; }
    int nx = N >> 5;
    int n0 = (bi % nx) * 32;
    int k0 = (bi / nx) * 32;
    __shared__ float t[32][33];
    int tx = threadIdx.x & 31, ty = threadIdx.x >> 5;   // 32 x 8
#pragma unroll
    for (int r = 0; r < 4; ++r)
        t[ty + r * 8][tx] = W[(size_t)(k0 + ty + r * 8) * N + n0 + tx];
    __syncthreads();
#pragma unroll
    for (int r = 0; r < 4; ++r)
        WT[(size_t)(n0 + ty + r * 8) * K + k0 + tx] = (bf16)t[tx][ty + r * 8];
}

// ---------------- MFMA GEMM: C[M,N] = act(A @ Bt^T + bias) (+resid) ----------
// Templated tile BM x BN (BM,BN in {64,128}), 256 threads = 4 waves (2x2).
// 1D grid of nbm*nbn blocks, XCD-grouped decode: all nbm row-blocks of a
// B col-panel land on the same XCD (requires nbn % 8 == 0).
template <int BM, int BN, int ACT, bool RESID, bool OUTBF, int BMODE, bool NTAIL>
__global__ __launch_bounds__(256) void mgemm_k(const bf16* __restrict__ A,
                                               const void* __restrict__ Btv,
                                               const float* __restrict__ bias,
                                               const float* __restrict__ resid,
                                               void* __restrict__ Cv,
                                               int N, int K, int nbm, int nbn) {
    constexpr int MI = BM / 32;
    constexpr int NJ = BN / 32;
    __shared__ bf16 As[BM * 32];
    __shared__ bf16 Bs[BN * 32];
    const int tid = threadIdx.x;
    const int lane = tid & 63;
    const int wid = tid >> 6;

    // XCD-grouped decode: xcd = col % 8, rows consecutive within XCD queue.
    const int bfl = blockIdx.x;
    const int xcd = bfl & 7;
    const int t1 = bfl >> 3;
    const int rr = t1 % nbm;
    const int cg = t1 / nbm;
    const int bm = rr * BM;
    const int bn = (cg * 8 + xcd) * BN;

    const int wr = (wid >> 1) * (BM / 2);
    const int wc = (wid & 1) * (BN / 2);
    const int l15 = lane & 15;
    const int l4 = lane >> 4;

    f32x4 acc[MI][NJ] = {};

    for (int k0 = 0; k0 < K; k0 += 32) {
        // ---- stage A (BM x 32 bf16) via global_load_lds ----
#pragma unroll
        for (int u = 0; u < BM / 64; ++u) {
            int ch = u * 256 + tid;
            gload_lds16(A + (size_t)(bm + (ch >> 2)) * K + k0 + (ch & 3) * 8,
                        &As[u * 2048 + wid * 512]);
        }
        if (BMODE == 0) {
            const bf16* B = (const bf16*)Btv;
#pragma unroll
            for (int u = 0; u < BN / 64; ++u) {
                int ch = u * 256 + tid;
                gload_lds16(B + (size_t)(bn + (ch >> 2)) * K + k0 + (ch & 3) * 8,
                            &Bs[u * 2048 + wid * 512]);
            }
        } else {
            const float* B = (const float*)Btv;
#pragma unroll
            for (int it = 0; it < BN / 64; ++it) {
                int gi = it * 256 + tid;
                int n = bn + (gi >> 2);
                if (NTAIL && n >= N) n = N - 1;
                const float* g = B + (size_t)n * K + k0 + (gi & 3) * 8;
                float4 f0 = *(const float4*)g;
                float4 f1 = *(const float4*)(g + 4);
                bf16x8 pk;
                pk[0] = (bf16)f0.x; pk[1] = (bf16)f0.y; pk[2] = (bf16)f0.z; pk[3] = (bf16)f0.w;
                pk[4] = (bf16)f1.x; pk[5] = (bf16)f1.y; pk[6] = (bf16)f1.z; pk[7] = (bf16)f1.w;
                *(bf16x8*)&Bs[gi * 8] = pk;
            }
        }
        __syncthreads();

        bf16x8 a[MI], b[NJ];
        const int ko = l4 * 8;
#pragma unroll
        for (int i = 0; i < MI; ++i)
            a[i] = *(const bf16x8*)&As[(wr + i * 16 + l15) * 32 + ko];
#pragma unroll
        for (int j = 0; j < NJ; ++j)
            b[j] = *(const bf16x8*)&Bs[(wc + j * 16 + l15) * 32 + ko];
#pragma unroll
        for (int i = 0; i < MI; ++i)
#pragma unroll
            for (int j = 0; j < NJ; ++j)
                acc[i][j] = __builtin_amdgcn_mfma_f32_16x16x32_bf16(a[i], b[j], acc[i][j], 0, 0, 0);
        __syncthreads();
    }

#pragma unroll
    for (int i = 0; i < MI; ++i) {
        int row0 = bm + wr + i * 16 + l4 * 4;
#pragma unroll
        for (int j = 0; j < NJ; ++j) {
            int col = bn + wc + j * 16 + l15;
            if (NTAIL && col >= N) continue;
            float bv = bias ? bias[col] : 0.f;
#pragma unroll
            for (int r = 0; r < 4; ++r) {
                float v = acc[i][j][r] + bv;
                if (ACT == 1) v = gelu_f(v);
                size_t idx = (size_t)(row0 + r) * N + col;
                if (RESID) v += resid[idx];
                if (OUTBF) ((bf16*)Cv)[idx] = (bf16)v;
                else       ((float*)Cv)[idx] = v;
            }
        }
    }
}

// ---------------- MFMA flash attention ----------------
// qkv: [T][3D] bf16. Grid (qt=T/64, h). Block 256 = 4 waves, wave owns 16 q-rows.
// Swapped QK^T (S^T = K·Q^T) so softmax per q is lane-local + 2 shuffles.
__global__ __launch_bounds__(256) void fattn_k(const bf16* __restrict__ qkv,
                                               const float* __restrict__ amask,
                                               bf16* __restrict__ out) {
    __shared__ bf16 Ks[64 * 64];      // [kr][d], rows 128B, XOR-swizzled
    __shared__ bf16 Vt[64 * 64];      // [d][k], rows 128B, XOR-swizzled
    __shared__ bf16 Pw[4][16 * 64];   // per-wave P [q][k], XOR-swizzled
    __shared__ float addb[Tn];        // attention-mask additive bias
    __shared__ float bcast[4][16];    // per-wave row-stat broadcast

    const int qt = blockIdx.x;
    const int hh = blockIdx.y;
    const int tid = threadIdx.x;
    const int lane = tid & 63;
    const int wq = tid >> 6;
    const int l15 = lane & 15;
    const int g = lane >> 4;

    const int qglob = qt * 64 + wq * 16 + l15;
    const int nkt = qt + 1;
    const int kmax = nkt * 64;

    for (int i = tid; i < kmax; i += 256)
        addb[i] = (1.0f - amask[i]) * -3.0e38f;

    // Q fragments in registers (row qglob, cols h*64 + s*32 + g*8)
    bf16x8 qreg[2];
    {
        const bf16* qp = qkv + (size_t)qglob * (3 * Dm) + hh * HDn + g * 8;
        qreg[0] = *(const bf16x8*)qp;
        qreg[1] = *(const bf16x8*)(qp + 32);
    }

    f32x4 accO[4] = {};               // O[q=4g+r][d=16nf+l15]
    float mrun = -3.0e38f, lrun = 0.f;

    for (int kt = 0; kt < nkt; ++kt) {
        const int kb = kt * 64;
        __syncthreads();   // previous tile fully consumed
        // ---- stage K tile [64][64]: 512 x 16B chunks ----
#pragma unroll
        for (int t2 = 0; t2 < 2; ++t2) {
            int c = tid + t2 * 256;
            int kr = c >> 3;             // 0..63
            int d8 = (c & 7) * 8;        // 0..56
            const bf16* gp = qkv + (size_t)(kb + kr) * (3 * Dm) + Dm + hh * HDn + d8;
            bf16x8 v = *(const bf16x8*)gp;
            *(bf16x8*)((char*)Ks + kr * 128 + ((d8 * 2) ^ ((kr & 7) << 4))) = v;
        }
        // ---- stage V transposed: Vt[d][k] ----
#pragma unroll
        for (int t2 = 0; t2 < 2; ++t2) {
            int c = tid + t2 * 256;
            int k = c >> 3, d0 = (c & 7) * 8;
            const bf16* gp = qkv + (size_t)(kb + k) * (3 * Dm) + 2 * Dm + hh * HDn + d0;
            bf16x8 v = *(const bf16x8*)gp;
#pragma unroll
            for (int j = 0; j < 8; ++j) {
                int d = d0 + j;
                *(bf16*)((char*)Vt + d * 128 + ((2 * k) ^ ((d & 7) << 4))) = v[j];
            }
        }
        __syncthreads();

        // ---- S^T = K · Q^T ----
        f32x4 accS[4] = {};
#pragma unroll
        for (int s = 0; s < 2; ++s)
#pragma unroll
            for (int mf = 0; mf < 4; ++mf) {
                int kr = mf * 16 + l15;
                bf16x8 af = *(const bf16x8*)((char*)Ks + kr * 128 + ((s * 64 + g * 16) ^ ((kr & 7) << 4)));
                accS[mf] = __builtin_amdgcn_mfma_f32_16x16x32_bf16(af, qreg[s], accS[mf], 0, 0, 0);
            }

        // ---- online softmax (stats per q = l15) ----
        float p[16];
        float tmax = -3.0e38f;
#pragma unroll
        for (int mf = 0; mf < 4; ++mf)
#pragma unroll
            for (int r = 0; r < 4; ++r) {
                int k = kb + mf * 16 + g * 4 + r;
                float sv = accS[mf][r] * 0.125f + addb[k];
                if (k > qglob) sv = -3.0e38f;     // causal
                p[mf * 4 + r] = sv;
                tmax = fmaxf(tmax, sv);
            }
        tmax = fmaxf(tmax, __shfl_xor(tmax, 16, 64));
        tmax = fmaxf(tmax, __shfl_xor(tmax, 32, 64));
        float mnew = fmaxf(mrun, tmax);
        float alpha = expf(mrun - mnew);
        float psum = 0.f;
#pragma unroll
        for (int i = 0; i < 16; ++i) { float e = expf(p[i] - mnew); p[i] = e; psum += e; }
        psum += __shfl_xor(psum, 16, 64);
        psum += __shfl_xor(psum, 32, 64);
        lrun = lrun * alpha + psum;
        mrun = mnew;

        // rescale O by alpha (per q-row broadcast via LDS, same-wave in-order DS)
        if (g == 0) bcast[wq][l15] = alpha;
        f32x4 av = *(f32x4*)&bcast[wq][g * 4];
#pragma unroll
        for (int nf = 0; nf < 4; ++nf)
#pragma unroll
            for (int r = 0; r < 4; ++r) accO[nf][r] *= av[r];

        // ---- P (bf16) -> per-wave LDS, re-read as PV A-fragments ----
        char* pw = (char*)Pw[wq];
#pragma unroll
        for (int mf = 0; mf < 4; ++mf) {
            bf16x4 pk;
            pk[0] = (bf16)p[mf * 4 + 0]; pk[1] = (bf16)p[mf * 4 + 1];
            pk[2] = (bf16)p[mf * 4 + 2]; pk[3] = (bf16)p[mf * 4 + 3];
            *(bf16x4*)(pw + l15 * 128 + ((32 * mf + 8 * g) ^ ((l15 & 7) << 4))) = pk;
        }
        bf16x8 pa[2];
#pragma unroll
        for (int s = 0; s < 2; ++s)
            pa[s] = *(const bf16x8*)(pw + l15 * 128 + ((s * 64 + g * 16) ^ ((l15 & 7) << 4)));

        // ---- O += P · V ----
#pragma unroll
        for (int s = 0; s < 2; ++s)
#pragma unroll
            for (int nf = 0; nf < 4; ++nf) {
                int d = nf * 16 + l15;
                bf16x8 bfg = *(const bf16x8*)((char*)Vt + d * 128 + ((s * 64 + g * 16) ^ ((d & 7) << 4)));
                accO[nf] = __builtin_amdgcn_mfma_f32_16x16x32_bf16(pa[s], bfg, accO[nf], 0, 0, 0);
            }
    }

    // ---- epilogue: O /= l, write bf16 ----
    if (g == 0) bcast[wq][l15] = 1.0f / lrun;
    f32x4 lv = *(f32x4*)&bcast[wq][g * 4];
#pragma unroll
    for (int nf = 0; nf < 4; ++nf)
#pragma unroll
        for (int r = 0; r < 4; ++r) {
            int row = qt * 64 + wq * 16 + 4 * g + r;
            int col = hh * HDn + nf * 16 + l15;
            out[(size_t)row * Dm + col] = (bf16)(accO[nf][r] * lv[r]);
        }
}

// ---------------- launch ----------------
extern "C" void kernel_launch(void* const* d_in, const int* in_sizes, int n_in,
                              void* d_out, int out_size, void* d_ws, size_t ws_size,
                              hipStream_t stream) {
    const int*   x      = (const int*)d_in[0];
    const float* amask  = (const float*)d_in[1];
    const float* tok    = (const float*)d_in[2];
    const float* pos    = (const float*)d_in[3];
    const float* ln1_g  = (const float*)d_in[4];
    const float* ln1_b  = (const float*)d_in[5];
    const float* qkv_w  = (const float*)d_in[6];
    const float* qkv_b  = (const float*)d_in[7];
    const float* out_w  = (const float*)d_in[8];
    const float* out_b  = (const float*)d_in[9];
    const float* ln2_g  = (const float*)d_in[10];
    const float* ln2_b  = (const float*)d_in[11];
    const float* fc1_w  = (const float*)d_in[12];
    const float* fc1_b  = (const float*)d_in[13];
    const float* fc2_w  = (const float*)d_in[14];
    const float* fc2_b  = (const float*)d_in[15];
    const float* lnf_g  = (const float*)d_in[16];
    const float* lnf_b  = (const float*)d_in[17];
    const float* lm_w   = (const float*)d_in[18];

    char* ws = (char*)d_ws;
    float* h      = (float*)(ws + 0);                       // 4 MB
    bf16*  qkv_bf = (bf16*) (ws + (4u << 20));              // 6 MB
    bf16*  xn_bf  = (bf16*) (ws + (16u << 20));             // 2 MB
    bf16*  wv_bf  = (bf16*) (ws + (18u << 20));             // 2 MB
    bf16*  ff1_bf = (bf16*) (ws + (20u << 20));             // 8 MB
    bf16*  Wbuf   = (bf16*) (ws + (28u << 20));             // 24 MB
    bf16* qT  = Wbuf;
    bf16* oT  = qT  + 3145728;
    bf16* f1T = oT  + 1048576;
    bf16* f2T = f1T + 4194304;
    float* outf = (float*)d_out;

    embed_k<<<Tn, 256, 0, stream>>>(x, tok, pos, h);

    for (int l = 0; l < Lnum; ++l) {
        const float* l1g = ln1_g + (size_t)l * Dm;
        const float* l1b = ln1_b + (size_t)l * Dm;
        const float* qw  = qkv_w + (size_t)l * Dm * 3 * Dm;
        const float* qb  = qkv_b + (size_t)l * 3 * Dm;
        const float* ow  = out_w + (size_t)l * Dm * Dm;
        const float* ob  = out_b + (size_t)l * Dm;
        const float* l2g = ln2_g + (size_t)l * Dm;
        const float* l2b = ln2_b + (size_t)l * Dm;
        const float* f1w = fc1_w + (size_t)l * Dm * 4 * Dm;
        const float* f1b = fc1_b + (size_t)l * 4 * Dm;
        const float* f2w = fc2_w + (size_t)l * 4 * Dm * Dm;
        const float* f2b = fc2_b + (size_t)l * Dm;

        tconv4_k<<<12288, 256, 0, stream>>>(qw, ow, f1w, f2w, qT, oT, f1T, f2T);
        ln_k<<<Tn, 256, 0, stream>>>(h, l1g, l1b, xn_bf);
        // qkv = xn @ qw + qb (bf16 out): 64x128 tiles, 16x24 = 384 blocks
        mgemm_k<64, 128, 0, false, true, 0, false><<<384, 256, 0, stream>>>(
            xn_bf, qT, qb, nullptr, qkv_bf, 3 * Dm, Dm, 16, 24);
        // flash attention
        fattn_k<<<dim3(Tn / 64, Hn), 256, 0, stream>>>(qkv_bf, amask, wv_bf);
        // h = h + wv @ ow + ob: 64x64 tiles, 16x16 = 256 blocks
        mgemm_k<64, 64, 0, true, false, 0, false><<<256, 256, 0, stream>>>(
            wv_bf, oT, ob, h, h, Dm, Dm, 16, 16);
        ln_k<<<Tn, 256, 0, stream>>>(h, l2g, l2b, xn_bf);
        // ff1 = gelu(xn @ f1w + f1b): 128x128 tiles, 8x32 = 256 blocks
        mgemm_k<128, 128, 1, false, true, 0, false><<<256, 256, 0, stream>>>(
            xn_bf, f1T, f1b, nullptr, ff1_bf, 4 * Dm, Dm, 8, 32);
        // h = h + ff1 @ f2w + f2b: 64x64 tiles, 16x16 = 256 blocks
        mgemm_k<64, 64, 0, true, false, 0, false><<<256, 256, 0, stream>>>(
            ff1_bf, f2T, f2b, h, h, Dm, 4 * Dm, 16, 16);
    }

    ln_k<<<Tn, 256, 0, stream>>>(h, lnf_g, lnf_b, xn_bf);
    // logits = xn @ lm_w^T: 128x128 tiles, nbn padded 393 -> 400 (NTAIL)
    mgemm_k<128, 128, 0, false, false, 1, true><<<8 * 400, 256, 0, stream>>>(
        xn_bf, lm_w, nullptr, nullptr, outf, Vn, Dm, 8, 400);
}

// Round 7
// 2307.467 us; speedup vs baseline: 12.9050x; 1.0957x over previous
//
#include <hip/hip_runtime.h>
#include <hip/hip_bf16.h>
#include <math.h>

// GPT-2 small forward: L=12, T=1024, D=1024, H=16, HD=64, V=50257, B=1
#define Lnum 12
#define Tn 1024
#define Dm 1024
#define Hn 16
#define HDn 64
#define Vn 50257

typedef __bf16 bf16;
typedef __bf16 bf16x4 __attribute__((ext_vector_type(4)));
typedef __bf16 bf16x8 __attribute__((ext_vector_type(8)));
typedef float f32x4 __attribute__((ext_vector_type(4)));

__device__ __forceinline__ void gload_lds16(const void* g, void* l) {
    __builtin_amdgcn_global_load_lds(
        (const __attribute__((address_space(1))) void*)g,
        (__attribute__((address_space(3))) void*)l, 16, 0, 0);
}

__device__ __forceinline__ float gelu_f(float x) {
    const float c = 0.7978845608028654f; // sqrt(2/pi)
    return 0.5f * x * (1.0f + tanhf(c * (x + 0.044715f * x * x * x)));
}

// ---------------- embedding (float4) ----------------
__global__ __launch_bounds__(256) void embed_k(const int* __restrict__ x,
                                               const float* __restrict__ tok,
                                               const float* __restrict__ pos,
                                               float* __restrict__ h) {
    int t = blockIdx.x;
    int id = x[t];
    const float4* tr = (const float4*)(tok + (size_t)id * Dm);
    const float4* pr = (const float4*)(pos + (size_t)t * Dm);
    float4* hr = (float4*)(h + (size_t)t * Dm);
    int i = threadIdx.x;
    float4 a = tr[i], b = pr[i];
    hr[i] = make_float4(a.x + b.x, a.y + b.y, a.z + b.z, a.w + b.w);
}

// ---------------- fp32 -> bf16 streaming convert ----------------
__global__ __launch_bounds__(256) void cvt_k(const float* __restrict__ in,
                                             bf16* __restrict__ out, int n8) {
    int stride = gridDim.x * 256;
    for (int i = blockIdx.x * 256 + threadIdx.x; i < n8; i += stride) {
        float4 f0 = ((const float4*)in)[i * 2];
        float4 f1 = ((const float4*)in)[i * 2 + 1];
        bf16x8 pk;
        pk[0] = (bf16)f0.x; pk[1] = (bf16)f0.y; pk[2] = (bf16)f0.z; pk[3] = (bf16)f0.w;
        pk[4] = (bf16)f1.x; pk[5] = (bf16)f1.y; pk[6] = (bf16)f1.z; pk[7] = (bf16)f1.w;
        *(bf16x8*)(out + (size_t)i * 8) = pk;
    }
}

// ---------------- layernorm (fp32 in, bf16 out, float4 loads) ----------------
__global__ __launch_bounds__(256) void ln_k(const float* __restrict__ x,
                                            const float* __restrict__ g,
                                            const float* __restrict__ b,
                                            bf16* __restrict__ y) {
    int row = blockIdx.x;
    int tid = threadIdx.x;
    const float* xr = x + (size_t)row * Dm;
    float4 v = ((const float4*)xr)[tid];
    float s = v.x + v.y + v.z + v.w;
    float s2 = v.x * v.x + v.y * v.y + v.z * v.z + v.w * v.w;
    __shared__ float rs[256], rs2[256];
    rs[tid] = s; rs2[tid] = s2;
    __syncthreads();
    for (int off = 128; off; off >>= 1) {
        if (tid < off) { rs[tid] += rs[tid + off]; rs2[tid] += rs2[tid + off]; }
        __syncthreads();
    }
    float mean = rs[0] * (1.0f / Dm);
    float var = rs2[0] * (1.0f / Dm) - mean * mean;
    float inv = rsqrtf(var + 1e-5f);
    float4 gg = ((const float4*)g)[tid];
    float4 bb = ((const float4*)b)[tid];
    bf16x4 pk;
    pk[0] = (bf16)((v.x - mean) * inv * gg.x + bb.x);
    pk[1] = (bf16)((v.y - mean) * inv * gg.y + bb.y);
    pk[2] = (bf16)((v.z - mean) * inv * gg.z + bb.z);
    pk[3] = (bf16)((v.w - mean) * inv * gg.w + bb.w);
    *(bf16x4*)(y + (size_t)row * Dm + tid * 4) = pk;
}

// ---------------- fused per-layer weight transpose+convert ----------------
__global__ __launch_bounds__(256) void tconv4_k(const float* __restrict__ qw,
                                                const float* __restrict__ ow,
                                                const float* __restrict__ f1,
                                                const float* __restrict__ f2,
                                                bf16* __restrict__ qT, bf16* __restrict__ oT,
                                                bf16* __restrict__ f1T, bf16* __restrict__ f2T) {
    int blk = blockIdx.x;
    const float* W; bf16* WT; int K, N, bi;
    if (blk < 3072)      { W = qw; WT = qT;  K = 1024; N = 3072; bi = blk; }
    else if (blk < 4096) { W = ow; WT = oT;  K = 1024; N = 1024; bi = blk - 3072; }
    else if (blk < 8192) { W = f1; WT = f1T; K = 1024; N = 4096; bi = blk - 4096; }
    else                 { W = f2; WT = f2T; K = 4096; N = 1024; bi = blk - 8192; }
    int nx = N >> 5;
    int n0 = (bi % nx) * 32;
    int k0 = (bi / nx) * 32;
    __shared__ float t[32][33];
    int tx = threadIdx.x & 31, ty = threadIdx.x >> 5;   // 32 x 8
#pragma unroll
    for (int r = 0; r < 4; ++r)
        t[ty + r * 8][tx] = W[(size_t)(k0 + ty + r * 8) * N + n0 + tx];
    __syncthreads();
#pragma unroll
    for (int r = 0; r < 4; ++r)
        WT[(size_t)(n0 + ty + r * 8) * K + k0 + tx] = (bf16)t[tx][ty + r * 8];
}

// ---------------- MFMA GEMM: C[M,N] = act(A @ Bt^T + bias) (+resid) ----------
// BK=64, rows 128B, XOR-swizzled (byte ^= (row&7)<<4).
// BMODE 0: Bt bf16, gload_lds with pre-swizzled global k-offset (linear LDS dest).
// BMODE 1: Bt fp32, reg-stage + convert + swizzled ds_write (fallback path).
// 1D grid, XCD-grouped decode (nbn % 8 == 0).
template <int BM, int BN, int ACT, bool RESID, bool OUTBF, int BMODE, bool NTAIL>
__global__ __launch_bounds__(256) void mgemm_k(const bf16* __restrict__ A,
                                               const void* __restrict__ Btv,
                                               const float* __restrict__ bias,
                                               const float* __restrict__ resid,
                                               void* __restrict__ Cv,
                                               int N, int K, int nbm, int nbn) {
    constexpr int MI = BM / 32;
    constexpr int NJ = BN / 32;
    __shared__ bf16 As[BM * 64];
    __shared__ bf16 Bs[BN * 64];
    const int tid = threadIdx.x;
    const int lane = tid & 63;
    const int wid = tid >> 6;

    // XCD-grouped decode: xcd = col % 8, rows consecutive within XCD queue.
    const int bfl = blockIdx.x;
    const int xcd = bfl & 7;
    const int t1 = bfl >> 3;
    const int rr = t1 % nbm;
    const int cg = t1 / nbm;
    const int bm = rr * BM;
    const int bn = (cg * 8 + xcd) * BN;

    const int wr = (wid >> 1) * (BM / 2);
    const int wc = (wid & 1) * (BN / 2);
    const int l15 = lane & 15;
    const int l4 = lane >> 4;

    f32x4 acc[MI][NJ] = {};

    for (int k0 = 0; k0 < K; k0 += 64) {
        // ---- stage A (BM x 64 bf16): linear LDS dest, pre-swizzled global src ----
#pragma unroll
        for (int u = 0; u < BM / 32; ++u) {
            int ch = u * 256 + tid;
            int row = ch >> 3;
            int cb = (ch & 7) * 16;                        // byte offset in 128B row
            int ksw = (cb ^ ((row & 7) << 4)) >> 1;        // swizzled k-element offset
            gload_lds16(A + (size_t)(bm + row) * K + k0 + ksw, &As[u * 2048 + wid * 512]);
        }
        if (BMODE == 0) {
            const bf16* B = (const bf16*)Btv;
#pragma unroll
            for (int u = 0; u < BN / 32; ++u) {
                int ch = u * 256 + tid;
                int row = ch >> 3;
                int cb = (ch & 7) * 16;
                int ksw = (cb ^ ((row & 7) << 4)) >> 1;
                gload_lds16(B + (size_t)(bn + row) * K + k0 + ksw, &Bs[u * 2048 + wid * 512]);
            }
        } else {
            const float* B = (const float*)Btv;
#pragma unroll
            for (int it = 0; it < BN / 32; ++it) {
                int gi = it * 256 + tid;
                int row = gi >> 3;
                int cb = (gi & 7) * 16;
                int n = bn + row;
                if (NTAIL && n >= N) n = N - 1;
                const float* g = B + (size_t)n * K + k0 + (gi & 7) * 8;
                float4 f0 = *(const float4*)g;
                float4 f1 = *(const float4*)(g + 4);
                bf16x8 pk;
                pk[0] = (bf16)f0.x; pk[1] = (bf16)f0.y; pk[2] = (bf16)f0.z; pk[3] = (bf16)f0.w;
                pk[4] = (bf16)f1.x; pk[5] = (bf16)f1.y; pk[6] = (bf16)f1.z; pk[7] = (bf16)f1.w;
                *(bf16x8*)((char*)Bs + row * 128 + (cb ^ ((row & 7) << 4))) = pk;
            }
        }
        __syncthreads();

#pragma unroll
        for (int kk = 0; kk < 2; ++kk) {
            const int kb = kk * 64 + l4 * 16;   // byte offset of this k-fragment
            bf16x8 a[MI], b[NJ];
#pragma unroll
            for (int i = 0; i < MI; ++i) {
                int row = wr + i * 16 + l15;
                a[i] = *(const bf16x8*)((char*)As + row * 128 + (kb ^ ((row & 7) << 4)));
            }
#pragma unroll
            for (int j = 0; j < NJ; ++j) {
                int row = wc + j * 16 + l15;
                b[j] = *(const bf16x8*)((char*)Bs + row * 128 + (kb ^ ((row & 7) << 4)));
            }
#pragma unroll
            for (int i = 0; i < MI; ++i)
#pragma unroll
                for (int j = 0; j < NJ; ++j)
                    acc[i][j] = __builtin_amdgcn_mfma_f32_16x16x32_bf16(a[i], b[j], acc[i][j], 0, 0, 0);
        }
        __syncthreads();
    }

#pragma unroll
    for (int i = 0; i < MI; ++i) {
        int row0 = bm + wr + i * 16 + l4 * 4;
#pragma unroll
        for (int j = 0; j < NJ; ++j) {
            int col = bn + wc + j * 16 + l15;
            if (NTAIL && col >= N) continue;
            float bv = bias ? bias[col] : 0.f;
#pragma unroll
            for (int r = 0; r < 4; ++r) {
                float v = acc[i][j][r] + bv;
                if (ACT == 1) v = gelu_f(v);
                size_t idx = (size_t)(row0 + r) * N + col;
                if (RESID) v += resid[idx];
                if (OUTBF) ((bf16*)Cv)[idx] = (bf16)v;
                else       ((float*)Cv)[idx] = v;
            }
        }
    }
}

// ---------------- MFMA flash attention ----------------
// qkv: [T][3D] bf16. Grid (qt=T/64, h). Block 256 = 4 waves, wave owns 16 q-rows.
// Swapped QK^T (S^T = K·Q^T) so softmax per q is lane-local + 2 shuffles.
__global__ __launch_bounds__(256) void fattn_k(const bf16* __restrict__ qkv,
                                               const float* __restrict__ amask,
                                               bf16* __restrict__ out) {
    __shared__ bf16 Ks[64 * 64];      // [kr][d], rows 128B, XOR-swizzled
    __shared__ bf16 Vt[64 * 64];      // [d][k], rows 128B, XOR-swizzled
    __shared__ bf16 Pw[4][16 * 64];   // per-wave P [q][k], XOR-swizzled
    __shared__ float addb[Tn];        // attention-mask additive bias
    __shared__ float bcast[4][16];    // per-wave row-stat broadcast

    const int qt = blockIdx.x;
    const int hh = blockIdx.y;
    const int tid = threadIdx.x;
    const int lane = tid & 63;
    const int wq = tid >> 6;
    const int l15 = lane & 15;
    const int g = lane >> 4;

    const int qglob = qt * 64 + wq * 16 + l15;
    const int nkt = qt + 1;
    const int kmax = nkt * 64;

    for (int i = tid; i < kmax; i += 256)
        addb[i] = (1.0f - amask[i]) * -3.0e38f;

    // Q fragments in registers (row qglob, cols h*64 + s*32 + g*8)
    bf16x8 qreg[2];
    {
        const bf16* qp = qkv + (size_t)qglob * (3 * Dm) + hh * HDn + g * 8;
        qreg[0] = *(const bf16x8*)qp;
        qreg[1] = *(const bf16x8*)(qp + 32);
    }

    f32x4 accO[4] = {};               // O[q=4g+r][d=16nf+l15]
    float mrun = -3.0e38f, lrun = 0.f;

    for (int kt = 0; kt < nkt; ++kt) {
        const int kb = kt * 64;
        __syncthreads();   // previous tile fully consumed
        // ---- stage K tile [64][64]: 512 x 16B chunks ----
#pragma unroll
        for (int t2 = 0; t2 < 2; ++t2) {
            int c = tid + t2 * 256;
            int kr = c >> 3;             // 0..63
            int d8 = (c & 7) * 8;        // 0..56
            const bf16* gp = qkv + (size_t)(kb + kr) * (3 * Dm) + Dm + hh * HDn + d8;
            bf16x8 v = *(const bf16x8*)gp;
            *(bf16x8*)((char*)Ks + kr * 128 + ((d8 * 2) ^ ((kr & 7) << 4))) = v;
        }
        // ---- stage V transposed: Vt[d][k] ----
#pragma unroll
        for (int t2 = 0; t2 < 2; ++t2) {
            int c = tid + t2 * 256;
            int k = c >> 3, d0 = (c & 7) * 8;
            const bf16* gp = qkv + (size_t)(kb + k) * (3 * Dm) + 2 * Dm + hh * HDn + d0;
            bf16x8 v = *(const bf16x8*)gp;
#pragma unroll
            for (int j = 0; j < 8; ++j) {
                int d = d0 + j;
                *(bf16*)((char*)Vt + d * 128 + ((2 * k) ^ ((d & 7) << 4))) = v[j];
            }
        }
        __syncthreads();

        // ---- S^T = K · Q^T ----
        f32x4 accS[4] = {};
#pragma unroll
        for (int s = 0; s < 2; ++s)
#pragma unroll
            for (int mf = 0; mf < 4; ++mf) {
                int kr = mf * 16 + l15;
                bf16x8 af = *(const bf16x8*)((char*)Ks + kr * 128 + ((s * 64 + g * 16) ^ ((kr & 7) << 4)));
                accS[mf] = __builtin_amdgcn_mfma_f32_16x16x32_bf16(af, qreg[s], accS[mf], 0, 0, 0);
            }

        // ---- online softmax (stats per q = l15) ----
        float p[16];
        float tmax = -3.0e38f;
#pragma unroll
        for (int mf = 0; mf < 4; ++mf)
#pragma unroll
            for (int r = 0; r < 4; ++r) {
                int k = kb + mf * 16 + g * 4 + r;
                float sv = accS[mf][r] * 0.125f + addb[k];
                if (k > qglob) sv = -3.0e38f;     // causal
                p[mf * 4 + r] = sv;
                tmax = fmaxf(tmax, sv);
            }
        tmax = fmaxf(tmax, __shfl_xor(tmax, 16, 64));
        tmax = fmaxf(tmax, __shfl_xor(tmax, 32, 64));
        float mnew = fmaxf(mrun, tmax);
        float alpha = expf(mrun - mnew);
        float psum = 0.f;
#pragma unroll
        for (int i = 0; i < 16; ++i) { float e = expf(p[i] - mnew); p[i] = e; psum += e; }
        psum += __shfl_xor(psum, 16, 64);
        psum += __shfl_xor(psum, 32, 64);
        lrun = lrun * alpha + psum;
        mrun = mnew;

        // rescale O by alpha (per q-row broadcast via LDS, same-wave in-order DS)
        if (g == 0) bcast[wq][l15] = alpha;
        f32x4 av = *(f32x4*)&bcast[wq][g * 4];
#pragma unroll
        for (int nf = 0; nf < 4; ++nf)
#pragma unroll
            for (int r = 0; r < 4; ++r) accO[nf][r] *= av[r];

        // ---- P (bf16) -> per-wave LDS, re-read as PV A-fragments ----
        char* pw = (char*)Pw[wq];
#pragma unroll
        for (int mf = 0; mf < 4; ++mf) {
            bf16x4 pk;
            pk[0] = (bf16)p[mf * 4 + 0]; pk[1] = (bf16)p[mf * 4 + 1];
            pk[2] = (bf16)p[mf * 4 + 2]; pk[3] = (bf16)p[mf * 4 + 3];
            *(bf16x4*)(pw + l15 * 128 + ((32 * mf + 8 * g) ^ ((l15 & 7) << 4))) = pk;
        }
        bf16x8 pa[2];
#pragma unroll
        for (int s = 0; s < 2; ++s)
            pa[s] = *(const bf16x8*)(pw + l15 * 128 + ((s * 64 + g * 16) ^ ((l15 & 7) << 4)));

        // ---- O += P · V ----
#pragma unroll
        for (int s = 0; s < 2; ++s)
#pragma unroll
            for (int nf = 0; nf < 4; ++nf) {
                int d = nf * 16 + l15;
                bf16x8 bfg = *(const bf16x8*)((char*)Vt + d * 128 + ((s * 64 + g * 16) ^ ((d & 7) << 4)));
                accO[nf] = __builtin_amdgcn_mfma_f32_16x16x32_bf16(pa[s], bfg, accO[nf], 0, 0, 0);
            }
    }

    // ---- epilogue: O /= l, write bf16 ----
    if (g == 0) bcast[wq][l15] = 1.0f / lrun;
    f32x4 lv = *(f32x4*)&bcast[wq][g * 4];
#pragma unroll
    for (int nf = 0; nf < 4; ++nf)
#pragma unroll
        for (int r = 0; r < 4; ++r) {
            int row = qt * 64 + wq * 16 + 4 * g + r;
            int col = hh * HDn + nf * 16 + l15;
            out[(size_t)row * Dm + col] = (bf16)(accO[nf][r] * lv[r]);
        }
}

// ---------------- launch ----------------
extern "C" void kernel_launch(void* const* d_in, const int* in_sizes, int n_in,
                              void* d_out, int out_size, void* d_ws, size_t ws_size,
                              hipStream_t stream) {
    const int*   x      = (const int*)d_in[0];
    const float* amask  = (const float*)d_in[1];
    const float* tok    = (const float*)d_in[2];
    const float* pos    = (const float*)d_in[3];
    const float* ln1_g  = (const float*)d_in[4];
    const float* ln1_b  = (const float*)d_in[5];
    const float* qkv_w  = (const float*)d_in[6];
    const float* qkv_b  = (const float*)d_in[7];
    const float* out_w  = (const float*)d_in[8];
    const float* out_b  = (const float*)d_in[9];
    const float* ln2_g  = (const float*)d_in[10];
    const float* ln2_b  = (const float*)d_in[11];
    const float* fc1_w  = (const float*)d_in[12];
    const float* fc1_b  = (const float*)d_in[13];
    const float* fc2_w  = (const float*)d_in[14];
    const float* fc2_b  = (const float*)d_in[15];
    const float* lnf_g  = (const float*)d_in[16];
    const float* lnf_b  = (const float*)d_in[17];
    const float* lm_w   = (const float*)d_in[18];

    char* ws = (char*)d_ws;
    float* h      = (float*)(ws + 0);                       // 4 MB
    bf16*  qkv_bf = (bf16*) (ws + (4u << 20));              // 6 MB
    bf16*  xn_bf  = (bf16*) (ws + (16u << 20));             // 2 MB
    bf16*  wv_bf  = (bf16*) (ws + (18u << 20));             // 2 MB
    bf16*  ff1_bf = (bf16*) (ws + (20u << 20));             // 8 MB
    bf16*  Wbuf   = (bf16*) (ws + (28u << 20));             // 24 MB
    bf16* qT  = Wbuf;
    bf16* oT  = qT  + 3145728;
    bf16* f1T = oT  + 1048576;
    bf16* f2T = f1T + 4194304;
    bf16* lm_bf = (bf16*)(ws + (52u << 20));                // 100 MB (if ws allows)
    float* outf = (float*)d_out;

    const bool big_ws = ws_size >= ((size_t)153 << 20);

    embed_k<<<Tn, 256, 0, stream>>>(x, tok, pos, h);

    for (int l = 0; l < Lnum; ++l) {
        const float* l1g = ln1_g + (size_t)l * Dm;
        const float* l1b = ln1_b + (size_t)l * Dm;
        const float* qw  = qkv_w + (size_t)l * Dm * 3 * Dm;
        const float* qb  = qkv_b + (size_t)l * 3 * Dm;
        const float* ow  = out_w + (size_t)l * Dm * Dm;
        const float* ob  = out_b + (size_t)l * Dm;
        const float* l2g = ln2_g + (size_t)l * Dm;
        const float* l2b = ln2_b + (size_t)l * Dm;
        const float* f1w = fc1_w + (size_t)l * Dm * 4 * Dm;
        const float* f1b = fc1_b + (size_t)l * 4 * Dm;
        const float* f2w = fc2_w + (size_t)l * 4 * Dm * Dm;
        const float* f2b = fc2_b + (size_t)l * Dm;

        tconv4_k<<<12288, 256, 0, stream>>>(qw, ow, f1w, f2w, qT, oT, f1T, f2T);
        ln_k<<<Tn, 256, 0, stream>>>(h, l1g, l1b, xn_bf);
        // qkv = xn @ qw + qb (bf16 out): 64x128 tiles, 16x24 = 384 blocks
        mgemm_k<64, 128, 0, false, true, 0, false><<<384, 256, 0, stream>>>(
            xn_bf, qT, qb, nullptr, qkv_bf, 3 * Dm, Dm, 16, 24);
        // flash attention
        fattn_k<<<dim3(Tn / 64, Hn), 256, 0, stream>>>(qkv_bf, amask, wv_bf);
        // h = h + wv @ ow + ob: 64x64 tiles, 16x16 = 256 blocks
        mgemm_k<64, 64, 0, true, false, 0, false><<<256, 256, 0, stream>>>(
            wv_bf, oT, ob, h, h, Dm, Dm, 16, 16);
        ln_k<<<Tn, 256, 0, stream>>>(h, l2g, l2b, xn_bf);
        // ff1 = gelu(xn @ f1w + f1b): 128x128 tiles, 8x32 = 256 blocks
        mgemm_k<128, 128, 1, false, true, 0, false><<<256, 256, 0, stream>>>(
            xn_bf, f1T, f1b, nullptr, ff1_bf, 4 * Dm, Dm, 8, 32);
        // h = h + ff1 @ f2w + f2b: 64x64 tiles, 16x16 = 256 blocks
        mgemm_k<64, 64, 0, true, false, 0, false><<<256, 256, 0, stream>>>(
            ff1_bf, f2T, f2b, h, h, Dm, 4 * Dm, 16, 16);
    }

    ln_k<<<Tn, 256, 0, stream>>>(h, lnf_g, lnf_b, xn_bf);
    // logits = xn @ lm_w^T: 128x128 tiles, nbn padded 393 -> 400 (NTAIL)
    if (big_ws) {
        // pre-convert lm_w to bf16 (no transpose needed: already N x K), then BMODE 0
        cvt_k<<<2048, 256, 0, stream>>>(lm_w, lm_bf, (Vn * Dm) / 8);
        mgemm_k<128, 128, 0, false, false, 0, true><<<8 * 400, 256, 0, stream>>>(
            xn_bf, lm_bf, nullptr, nullptr, outf, Vn, Dm, 8, 400);
    } else {
        mgemm_k<128, 128, 0, false, false, 1, true><<<8 * 400, 256, 0, stream>>>(
            xn_bf, lm_w, nullptr, nullptr, outf, Vn, Dm, 8, 400);
    }
}

// Round 8
// 1864.838 us; speedup vs baseline: 15.9681x; 1.2374x over previous
//
#include <hip/hip_runtime.h>
#include <hip/hip_bf16.h>
#include <math.h>

// GPT-2 small forward: L=12, T=1024, D=1024, H=16, HD=64, V=50257, B=1
#define Lnum 12
#define Tn 1024
#define Dm 1024
#define Hn 16
#define HDn 64
#define Vn 50257

typedef __bf16 bf16;
typedef __bf16 bf16x4 __attribute__((ext_vector_type(4)));
typedef __bf16 bf16x8 __attribute__((ext_vector_type(8)));
typedef float f32x4 __attribute__((ext_vector_type(4)));

__device__ __forceinline__ void gload_lds16(const void* g, void* l) {
    __builtin_amdgcn_global_load_lds(
        (const __attribute__((address_space(1))) void*)g,
        (__attribute__((address_space(3))) void*)l, 16, 0, 0);
}

__device__ __forceinline__ float gelu_f(float x) {
    const float c = 0.7978845608028654f; // sqrt(2/pi)
    return 0.5f * x * (1.0f + tanhf(c * (x + 0.044715f * x * x * x)));
}

// ---------------- embedding (float4) ----------------
__global__ __launch_bounds__(256) void embed_k(const int* __restrict__ x,
                                               const float* __restrict__ tok,
                                               const float* __restrict__ pos,
                                               float* __restrict__ h) {
    int t = blockIdx.x;
    int id = x[t];
    const float4* tr = (const float4*)(tok + (size_t)id * Dm);
    const float4* pr = (const float4*)(pos + (size_t)t * Dm);
    float4* hr = (float4*)(h + (size_t)t * Dm);
    int i = threadIdx.x;
    float4 a = tr[i], b = pr[i];
    hr[i] = make_float4(a.x + b.x, a.y + b.y, a.z + b.z, a.w + b.w);
}

// ---------------- fp32 -> bf16 streaming convert ----------------
__global__ __launch_bounds__(256) void cvt_k(const float* __restrict__ in,
                                             bf16* __restrict__ out, int n8) {
    int stride = gridDim.x * 256;
    for (int i = blockIdx.x * 256 + threadIdx.x; i < n8; i += stride) {
        float4 f0 = ((const float4*)in)[i * 2];
        float4 f1 = ((const float4*)in)[i * 2 + 1];
        bf16x8 pk;
        pk[0] = (bf16)f0.x; pk[1] = (bf16)f0.y; pk[2] = (bf16)f0.z; pk[3] = (bf16)f0.w;
        pk[4] = (bf16)f1.x; pk[5] = (bf16)f1.y; pk[6] = (bf16)f1.z; pk[7] = (bf16)f1.w;
        *(bf16x8*)(out + (size_t)i * 8) = pk;
    }
}

// ---------------- layernorm (fp32 in, bf16 out, float4 loads) ----------------
__global__ __launch_bounds__(256) void ln_k(const float* __restrict__ x,
                                            const float* __restrict__ g,
                                            const float* __restrict__ b,
                                            bf16* __restrict__ y) {
    int row = blockIdx.x;
    int tid = threadIdx.x;
    const float* xr = x + (size_t)row * Dm;
    float4 v = ((const float4*)xr)[tid];
    float s = v.x + v.y + v.z + v.w;
    float s2 = v.x * v.x + v.y * v.y + v.z * v.z + v.w * v.w;
    __shared__ float rs[256], rs2[256];
    rs[tid] = s; rs2[tid] = s2;
    __syncthreads();
    for (int off = 128; off; off >>= 1) {
        if (tid < off) { rs[tid] += rs[tid + off]; rs2[tid] += rs2[tid + off]; }
        __syncthreads();
    }
    float mean = rs[0] * (1.0f / Dm);
    float var = rs2[0] * (1.0f / Dm) - mean * mean;
    float inv = rsqrtf(var + 1e-5f);
    float4 gg = ((const float4*)g)[tid];
    float4 bb = ((const float4*)b)[tid];
    bf16x4 pk;
    pk[0] = (bf16)((v.x - mean) * inv * gg.x + bb.x);
    pk[1] = (bf16)((v.y - mean) * inv * gg.y + bb.y);
    pk[2] = (bf16)((v.z - mean) * inv * gg.z + bb.z);
    pk[3] = (bf16)((v.w - mean) * inv * gg.w + bb.w);
    *(bf16x4*)(y + (size_t)row * Dm + tid * 4) = pk;
}

// ---------------- fused per-layer weight transpose+convert ----------------
__global__ __launch_bounds__(256) void tconv4_k(const float* __restrict__ qw,
                                                const float* __restrict__ ow,
                                                const float* __restrict__ f1,
                                                const float* __restrict__ f2,
                                                bf16* __restrict__ qT, bf16* __restrict__ oT,
                                                bf16* __restrict__ f1T, bf16* __restrict__ f2T) {
    int blk = blockIdx.x;
    const float* W; bf16* WT; int K, N, bi;
    if (blk < 3072)      { W = qw; WT = qT;  K = 1024; N = 3072; bi = blk; }
    else if (blk < 4096) { W = ow; WT = oT;  K = 1024; N = 1024; bi = blk - 3072; }
    else if (blk < 8192) { W = f1; WT = f1T; K = 1024; N = 4096; bi = blk - 4096; }
    else                 { W = f2; WT = f2T; K = 4096; N = 1024; bi = blk - 8192; }
    int nx = N >> 5;
    int n0 = (bi % nx) * 32;
    int k0 = (bi / nx) * 32;
    __shared__ float t[32][33];                         // t[k][n]
    int tx = threadIdx.x & 31, ty = threadIdx.x >> 5;   // 32 x 8
#pragma unroll
    for (int r = 0; r < 4; ++r)
        t[ty + r * 8][tx] = W[(size_t)(k0 + ty + r * 8) * N + n0 + tx];
    __syncthreads();
    // vectorized write: thread -> (row = n-offset, 4 consecutive k)
    int row = threadIdx.x >> 3;         // 0..31
    int k4 = (threadIdx.x & 7) * 4;     // 0..28
    bf16x4 pk;
#pragma unroll
    for (int j = 0; j < 4; ++j) pk[j] = (bf16)t[k4 + j][row];
    *(bf16x4*)(WT + (size_t)(n0 + row) * K + k0 + k4) = pk;
}

// ---------------- MFMA GEMM: C[M,N] = act(A @ Bt^T + bias) (+resid) ----------
// BK=64, rows 128B, XOR-swizzled (byte ^= (row&7)<<4).
// BMODE 0: Bt bf16, gload_lds with pre-swizzled global k-offset (linear LDS dest).
// BMODE 1: Bt fp32, reg-stage + convert + swizzled ds_write (fallback path).
// 1D grid, XCD-grouped decode (nbn % 8 == 0).
template <int BM, int BN, int ACT, bool RESID, bool OUTBF, int BMODE, bool NTAIL>
__global__ __launch_bounds__(256) void mgemm_k(const bf16* __restrict__ A,
                                               const void* __restrict__ Btv,
                                               const float* __restrict__ bias,
                                               const float* __restrict__ resid,
                                               void* __restrict__ Cv,
                                               int N, int K, int nbm, int nbn) {
    constexpr int MI = BM / 32;
    constexpr int NJ = BN / 32;
    __shared__ bf16 As[BM * 64];
    __shared__ bf16 Bs[BN * 64];
    const int tid = threadIdx.x;
    const int lane = tid & 63;
    const int wid = tid >> 6;

    // XCD-grouped decode: xcd = col % 8, rows consecutive within XCD queue.
    const int bfl = blockIdx.x;
    const int xcd = bfl & 7;
    const int t1 = bfl >> 3;
    const int rr = t1 % nbm;
    const int cg = t1 / nbm;
    const int bm = rr * BM;
    const int bn = (cg * 8 + xcd) * BN;

    const int wr = (wid >> 1) * (BM / 2);
    const int wc = (wid & 1) * (BN / 2);
    const int l15 = lane & 15;
    const int l4 = lane >> 4;

    f32x4 acc[MI][NJ] = {};

    for (int k0 = 0; k0 < K; k0 += 64) {
        // ---- stage A (BM x 64 bf16): linear LDS dest, pre-swizzled global src ----
#pragma unroll
        for (int u = 0; u < BM / 32; ++u) {
            int ch = u * 256 + tid;
            int row = ch >> 3;
            int cb = (ch & 7) * 16;                        // byte offset in 128B row
            int ksw = (cb ^ ((row & 7) << 4)) >> 1;        // swizzled k-element offset
            gload_lds16(A + (size_t)(bm + row) * K + k0 + ksw, &As[u * 2048 + wid * 512]);
        }
        if (BMODE == 0) {
            const bf16* B = (const bf16*)Btv;
#pragma unroll
            for (int u = 0; u < BN / 32; ++u) {
                int ch = u * 256 + tid;
                int row = ch >> 3;
                int cb = (ch & 7) * 16;
                int ksw = (cb ^ ((row & 7) << 4)) >> 1;
                gload_lds16(B + (size_t)(bn + row) * K + k0 + ksw, &Bs[u * 2048 + wid * 512]);
            }
        } else {
            const float* B = (const float*)Btv;
#pragma unroll
            for (int it = 0; it < BN / 32; ++it) {
                int gi = it * 256 + tid;
                int row = gi >> 3;
                int cb = (gi & 7) * 16;
                int n = bn + row;
                if (NTAIL && n >= N) n = N - 1;
                const float* g = B + (size_t)n * K + k0 + (gi & 7) * 8;
                float4 f0 = *(const float4*)g;
                float4 f1 = *(const float4*)(g + 4);
                bf16x8 pk;
                pk[0] = (bf16)f0.x; pk[1] = (bf16)f0.y; pk[2] = (bf16)f0.z; pk[3] = (bf16)f0.w;
                pk[4] = (bf16)f1.x; pk[5] = (bf16)f1.y; pk[6] = (bf16)f1.z; pk[7] = (bf16)f1.w;
                *(bf16x8*)((char*)Bs + row * 128 + (cb ^ ((row & 7) << 4))) = pk;
            }
        }
        __syncthreads();

#pragma unroll
        for (int kk = 0; kk < 2; ++kk) {
            const int kb = kk * 64 + l4 * 16;   // byte offset of this k-fragment
            bf16x8 a[MI], b[NJ];
#pragma unroll
            for (int i = 0; i < MI; ++i) {
                int row = wr + i * 16 + l15;
                a[i] = *(const bf16x8*)((char*)As + row * 128 + (kb ^ ((row & 7) << 4)));
            }
#pragma unroll
            for (int j = 0; j < NJ; ++j) {
                int row = wc + j * 16 + l15;
                b[j] = *(const bf16x8*)((char*)Bs + row * 128 + (kb ^ ((row & 7) << 4)));
            }
#pragma unroll
            for (int i = 0; i < MI; ++i)
#pragma unroll
                for (int j = 0; j < NJ; ++j)
                    acc[i][j] = __builtin_amdgcn_mfma_f32_16x16x32_bf16(a[i], b[j], acc[i][j], 0, 0, 0);
        }
        __syncthreads();
    }

#pragma unroll
    for (int i = 0; i < MI; ++i) {
        int row0 = bm + wr + i * 16 + l4 * 4;
#pragma unroll
        for (int j = 0; j < NJ; ++j) {
            int col = bn + wc + j * 16 + l15;
            if (NTAIL && col >= N) continue;
            float bv = bias ? bias[col] : 0.f;
#pragma unroll
            for (int r = 0; r < 4; ++r) {
                float v = acc[i][j][r] + bv;
                if (ACT == 1) v = gelu_f(v);
                size_t idx = (size_t)(row0 + r) * N + col;
                if (RESID) v += resid[idx];
                if (OUTBF) ((bf16*)Cv)[idx] = (bf16)v;
                else       ((float*)Cv)[idx] = v;
            }
        }
    }
}

// ---------------- MFMA flash attention ----------------
// QBLK=32, 128 threads = 2 waves (16 q-rows each), KVBLK=64.
// 1D grid of 512 blocks (2/CU): first 256 carry qt 0..15 ascending, second 256
// carry qt 31..16 descending -> LPT-style pairing balances causal load.
// Swapped QK^T (S^T = K.Q^T) so softmax per q is lane-local + 2 shuffles.
__global__ __launch_bounds__(128) void fattn_k(const bf16* __restrict__ qkv,
                                               const float* __restrict__ amask,
                                               bf16* __restrict__ out) {
    __shared__ bf16 Ks[64 * 64];      // [kr][d], rows 128B, XOR-swizzled
    __shared__ bf16 Vt[64 * 64];      // [d][k], rows 128B, XOR-swizzled
    __shared__ bf16 Pw[2][16 * 64];   // per-wave P [q][k], XOR-swizzled
    __shared__ float addb[Tn];        // attention-mask additive bias
    __shared__ float bcast[2][16];    // per-wave row-stat broadcast

    const int f = blockIdx.x;
    const int hh = f & 15;
    const int s = f >> 4;                       // 0..31
    const int qt = (s < 16) ? s : 47 - s;       // LPT pairing
    const int tid = threadIdx.x;
    const int lane = tid & 63;
    const int wq = tid >> 6;                    // 0..1
    const int l15 = lane & 15;
    const int g = lane >> 4;

    const int qglob = qt * 32 + wq * 16 + l15;
    const int nkt = (qt >> 1) + 1;
    const int kmax = nkt * 64;

    for (int i = tid; i < kmax; i += 128)
        addb[i] = (1.0f - amask[i]) * -3.0e38f;

    // Q fragments in registers (row qglob, cols h*64 + s2*32 + g*8)
    bf16x8 qreg[2];
    {
        const bf16* qp = qkv + (size_t)qglob * (3 * Dm) + hh * HDn + g * 8;
        qreg[0] = *(const bf16x8*)qp;
        qreg[1] = *(const bf16x8*)(qp + 32);
    }

    f32x4 accO[4] = {};               // O[q=4g+r][d=16nf+l15]
    float mrun = -3.0e38f, lrun = 0.f;

    for (int kt = 0; kt < nkt; ++kt) {
        const int kb = kt * 64;
        __syncthreads();   // previous tile fully consumed
        // ---- stage K tile [64][64]: 512 x 16B chunks ----
#pragma unroll
        for (int t2 = 0; t2 < 4; ++t2) {
            int c = tid + t2 * 128;
            int kr = c >> 3;             // 0..63
            int d8 = (c & 7) * 8;        // 0..56
            const bf16* gp = qkv + (size_t)(kb + kr) * (3 * Dm) + Dm + hh * HDn + d8;
            bf16x8 v = *(const bf16x8*)gp;
            *(bf16x8*)((char*)Ks + kr * 128 + ((d8 * 2) ^ ((kr & 7) << 4))) = v;
        }
        // ---- stage V transposed: Vt[d][k] ----
#pragma unroll
        for (int t2 = 0; t2 < 4; ++t2) {
            int c = tid + t2 * 128;
            int k = c >> 3, d0 = (c & 7) * 8;
            const bf16* gp = qkv + (size_t)(kb + k) * (3 * Dm) + 2 * Dm + hh * HDn + d0;
            bf16x8 v = *(const bf16x8*)gp;
#pragma unroll
            for (int j = 0; j < 8; ++j) {
                int d = d0 + j;
                *(bf16*)((char*)Vt + d * 128 + ((2 * k) ^ ((d & 7) << 4))) = v[j];
            }
        }
        __syncthreads();

        // ---- S^T = K . Q^T ----
        f32x4 accS[4] = {};
        __builtin_amdgcn_s_setprio(1);
#pragma unroll
        for (int s2 = 0; s2 < 2; ++s2)
#pragma unroll
            for (int mf = 0; mf < 4; ++mf) {
                int kr = mf * 16 + l15;
                bf16x8 af = *(const bf16x8*)((char*)Ks + kr * 128 + ((s2 * 64 + g * 16) ^ ((kr & 7) << 4)));
                accS[mf] = __builtin_amdgcn_mfma_f32_16x16x32_bf16(af, qreg[s2], accS[mf], 0, 0, 0);
            }
        __builtin_amdgcn_s_setprio(0);

        // ---- online softmax (stats per q = l15) ----
        float p[16];
        float tmax = -3.0e38f;
#pragma unroll
        for (int mf = 0; mf < 4; ++mf)
#pragma unroll
            for (int r = 0; r < 4; ++r) {
                int k = kb + mf * 16 + g * 4 + r;
                float sv = accS[mf][r] * 0.125f + addb[k];
                if (k > qglob) sv = -3.0e38f;     // causal
                p[mf * 4 + r] = sv;
                tmax = fmaxf(tmax, sv);
            }
        tmax = fmaxf(tmax, __shfl_xor(tmax, 16, 64));
        tmax = fmaxf(tmax, __shfl_xor(tmax, 32, 64));
        float mnew = fmaxf(mrun, tmax);
        float alpha = expf(mrun - mnew);
        float psum = 0.f;
#pragma unroll
        for (int i = 0; i < 16; ++i) { float e = expf(p[i] - mnew); p[i] = e; psum += e; }
        psum += __shfl_xor(psum, 16, 64);
        psum += __shfl_xor(psum, 32, 64);
        lrun = lrun * alpha + psum;
        mrun = mnew;

        // rescale O by alpha (per q-row broadcast via LDS, same-wave in-order DS)
        if (g == 0) bcast[wq][l15] = alpha;
        f32x4 av = *(f32x4*)&bcast[wq][g * 4];
#pragma unroll
        for (int nf = 0; nf < 4; ++nf)
#pragma unroll
            for (int r = 0; r < 4; ++r) accO[nf][r] *= av[r];

        // ---- P (bf16) -> per-wave LDS, re-read as PV A-fragments ----
        char* pw = (char*)Pw[wq];
#pragma unroll
        for (int mf = 0; mf < 4; ++mf) {
            bf16x4 pk;
            pk[0] = (bf16)p[mf * 4 + 0]; pk[1] = (bf16)p[mf * 4 + 1];
            pk[2] = (bf16)p[mf * 4 + 2]; pk[3] = (bf16)p[mf * 4 + 3];
            *(bf16x4*)(pw + l15 * 128 + ((32 * mf + 8 * g) ^ ((l15 & 7) << 4))) = pk;
        }
        bf16x8 pa[2];
#pragma unroll
        for (int s2 = 0; s2 < 2; ++s2)
            pa[s2] = *(const bf16x8*)(pw + l15 * 128 + ((s2 * 64 + g * 16) ^ ((l15 & 7) << 4)));

        // ---- O += P . V ----
        __builtin_amdgcn_s_setprio(1);
#pragma unroll
        for (int s2 = 0; s2 < 2; ++s2)
#pragma unroll
            for (int nf = 0; nf < 4; ++nf) {
                int d = nf * 16 + l15;
                bf16x8 bfg = *(const bf16x8*)((char*)Vt + d * 128 + ((s2 * 64 + g * 16) ^ ((d & 7) << 4)));
                accO[nf] = __builtin_amdgcn_mfma_f32_16x16x32_bf16(pa[s2], bfg, accO[nf], 0, 0, 0);
            }
        __builtin_amdgcn_s_setprio(0);
    }

    // ---- epilogue: O /= l, write bf16 ----
    if (g == 0) bcast[wq][l15] = 1.0f / lrun;
    f32x4 lv = *(f32x4*)&bcast[wq][g * 4];
#pragma unroll
    for (int nf = 0; nf < 4; ++nf)
#pragma unroll
        for (int r = 0; r < 4; ++r) {
            int row = qt * 32 + wq * 16 + 4 * g + r;
            int col = hh * HDn + nf * 16 + l15;
            out[(size_t)row * Dm + col] = (bf16)(accO[nf][r] * lv[r]);
        }
}

// ---------------- launch ----------------
extern "C" void kernel_launch(void* const* d_in, const int* in_sizes, int n_in,
                              void* d_out, int out_size, void* d_ws, size_t ws_size,
                              hipStream_t stream) {
    const int*   x      = (const int*)d_in[0];
    const float* amask  = (const float*)d_in[1];
    const float* tok    = (const float*)d_in[2];
    const float* pos    = (const float*)d_in[3];
    const float* ln1_g  = (const float*)d_in[4];
    const float* ln1_b  = (const float*)d_in[5];
    const float* qkv_w  = (const float*)d_in[6];
    const float* qkv_b  = (const float*)d_in[7];
    const float* out_w  = (const float*)d_in[8];
    const float* out_b  = (const float*)d_in[9];
    const float* ln2_g  = (const float*)d_in[10];
    const float* ln2_b  = (const float*)d_in[11];
    const float* fc1_w  = (const float*)d_in[12];
    const float* fc1_b  = (const float*)d_in[13];
    const float* fc2_w  = (const float*)d_in[14];
    const float* fc2_b  = (const float*)d_in[15];
    const float* lnf_g  = (const float*)d_in[16];
    const float* lnf_b  = (const float*)d_in[17];
    const float* lm_w   = (const float*)d_in[18];

    char* ws = (char*)d_ws;
    float* h      = (float*)(ws + 0);                       // 4 MB
    bf16*  qkv_bf = (bf16*) (ws + (4u << 20));              // 6 MB
    bf16*  xn_bf  = (bf16*) (ws + (16u << 20));             // 2 MB
    bf16*  wv_bf  = (bf16*) (ws + (18u << 20));             // 2 MB
    bf16*  ff1_bf = (bf16*) (ws + (20u << 20));             // 8 MB
    bf16*  Wbuf   = (bf16*) (ws + (28u << 20));             // 24 MB
    bf16* qT  = Wbuf;
    bf16* oT  = qT  + 3145728;
    bf16* f1T = oT  + 1048576;
    bf16* f2T = f1T + 4194304;
    bf16* lm_bf = (bf16*)(ws + (52u << 20));                // 100 MB (if ws allows)
    float* outf = (float*)d_out;

    const bool big_ws = ws_size >= ((size_t)153 << 20);

    embed_k<<<Tn, 256, 0, stream>>>(x, tok, pos, h);

    for (int l = 0; l < Lnum; ++l) {
        const float* l1g = ln1_g + (size_t)l * Dm;
        const float* l1b = ln1_b + (size_t)l * Dm;
        const float* qw  = qkv_w + (size_t)l * Dm * 3 * Dm;
        const float* qb  = qkv_b + (size_t)l * 3 * Dm;
        const float* ow  = out_w + (size_t)l * Dm * Dm;
        const float* ob  = out_b + (size_t)l * Dm;
        const float* l2g = ln2_g + (size_t)l * Dm;
        const float* l2b = ln2_b + (size_t)l * Dm;
        const float* f1w = fc1_w + (size_t)l * Dm * 4 * Dm;
        const float* f1b = fc1_b + (size_t)l * 4 * Dm;
        const float* f2w = fc2_w + (size_t)l * 4 * Dm * Dm;
        const float* f2b = fc2_b + (size_t)l * Dm;

        tconv4_k<<<12288, 256, 0, stream>>>(qw, ow, f1w, f2w, qT, oT, f1T, f2T);
        ln_k<<<Tn, 256, 0, stream>>>(h, l1g, l1b, xn_bf);
        // qkv = xn @ qw + qb (bf16 out): 64x64 tiles, 16x48 = 768 blocks (3/CU)
        mgemm_k<64, 64, 0, false, true, 0, false><<<768, 256, 0, stream>>>(
            xn_bf, qT, qb, nullptr, qkv_bf, 3 * Dm, Dm, 16, 48);
        // flash attention: 512 blocks x 128 thr, LPT-balanced causal
        fattn_k<<<512, 128, 0, stream>>>(qkv_bf, amask, wv_bf);
        // h = h + wv @ ow + ob: 32x64 tiles, 32x16 = 512 blocks (2/CU)
        mgemm_k<32, 64, 0, true, false, 0, false><<<512, 256, 0, stream>>>(
            wv_bf, oT, ob, h, h, Dm, Dm, 32, 16);
        ln_k<<<Tn, 256, 0, stream>>>(h, l2g, l2b, xn_bf);
        // ff1 = gelu(xn @ f1w + f1b): 64x64 tiles, 16x64 = 1024 blocks (4/CU)
        mgemm_k<64, 64, 1, false, true, 0, false><<<1024, 256, 0, stream>>>(
            xn_bf, f1T, f1b, nullptr, ff1_bf, 4 * Dm, Dm, 16, 64);
        // h = h + ff1 @ f2w + f2b: 32x64 tiles, 32x16 = 512 blocks (2/CU)
        mgemm_k<32, 64, 0, true, false, 0, false><<<512, 256, 0, stream>>>(
            ff1_bf, f2T, f2b, h, h, Dm, 4 * Dm, 32, 16);
    }

    ln_k<<<Tn, 256, 0, stream>>>(h, lnf_g, lnf_b, xn_bf);
    // logits = xn @ lm_w^T: 128x128 tiles, nbn padded 393 -> 400 (NTAIL)
    if (big_ws) {
        cvt_k<<<2048, 256, 0, stream>>>(lm_w, lm_bf, (Vn * Dm) / 8);
        mgemm_k<128, 128, 0, false, false, 0, true><<<8 * 400, 256, 0, stream>>>(
            xn_bf, lm_bf, nullptr, nullptr, outf, Vn, Dm, 8, 400);
    } else {
        mgemm_k<128, 128, 0, false, false, 1, true><<<8 * 400, 256, 0, stream>>>(
            xn_bf, lm_w, nullptr, nullptr, outf, Vn, Dm, 8, 400);
    }
}